// Round 1
// baseline (396.645 us; speedup 1.0000x reference)
//
#include <hip/hip_runtime.h>
#include <stdint.h>

#define S_LEN 2048
#define HID   2048
#define NH    32
#define NKV   8
#define HD    64
#define BATCH 2
#define NROWS (BATCH * S_LEN)      // 4096
#define QKVN  (NH*HD + 2*NKV*HD)   // 3072

typedef unsigned short u16;
typedef __bf16 bf16_t;
typedef bf16_t bf16x8 __attribute__((ext_vector_type(8)));
typedef float  f32x4  __attribute__((ext_vector_type(4)));
typedef u16    u16x8  __attribute__((ext_vector_type(8)));

#define LOG2E 1.4426950408889634f

__device__ __forceinline__ u16 f2bf(float f) {
    union { float f; uint32_t u; } v; v.f = f;
    uint32_t u = v.u;
    return (u16)((u + 0x7fffu + ((u >> 16) & 1u)) >> 16);
}

__device__ __forceinline__ void llds16(const void* g, void* l) {
    __builtin_amdgcn_global_load_lds(
        (const __attribute__((address_space(1))) void*)g,
        (__attribute__((address_space(3))) void*)l,
        16, 0, 0);
}

// ---------------- f32 -> bf16 convert (16B vectorized) ----------------
__global__ void cvt_f32_bf16(const float* __restrict__ src, u16* __restrict__ dst, int n8) {
    int i = blockIdx.x * blockDim.x + threadIdx.x;
    if (i >= n8) return;
    const float4* s = (const float4*)src;
    float4 a = s[2*(size_t)i], b = s[2*(size_t)i + 1];
    u16x8 r;
    r[0]=f2bf(a.x); r[1]=f2bf(a.y); r[2]=f2bf(a.z); r[3]=f2bf(a.w);
    r[4]=f2bf(b.x); r[5]=f2bf(b.y); r[6]=f2bf(b.z); r[7]=f2bf(b.w);
    *(u16x8*)(dst + 8*(size_t)i) = r;
}

// ---------------- concat bias (bq|bk|bv) ----------------
__global__ void build_bqkv(const float* __restrict__ bq, const float* __restrict__ bk,
                           const float* __restrict__ bv, float* __restrict__ bqkv) {
    int i = blockIdx.x * 256 + threadIdx.x;
    if (i >= QKVN) return;
    bqkv[i] = (i < 2048) ? bq[i] : (i < 2560 ? bk[i - 2048] : bv[i - 2560]);
}

// ---------------- RoPE table: cos at [0:65536), sin at [65536:131072) ----------------
__global__ void rope_table(float* __restrict__ tab) {
    int idx = blockIdx.x * 256 + threadIdx.x;   // s*32 + i
    if (idx >= S_LEN * 32) return;
    int i = idx & 31, s = idx >> 5;
    // inv_freq = 10000^(-i/32) = 2^(-i*log2(10000)/32)
    float invf = exp2f(-(float)i * (13.287712379549449f / 32.0f));
    float ang = (float)s * invf;
    float sn, cs;
    sincosf(ang, &sn, &cs);
    tab[idx] = cs;
    tab[S_LEN*32 + idx] = sn;
}

// ---------------- bf16 GEMM, C[M][N] = A[M][K] * Bw[N][K]^T + bias[n] (m97 structure) ----------------
__global__ __launch_bounds__(256) void gemm_bt(
    const u16* __restrict__ A, const u16* __restrict__ Bw,
    const float* __restrict__ bias, float* __restrict__ C,
    int M, int N, int K)
{
    const int nbm = M >> 7, nbn = N >> 7;
    const int nwg = nbm * nbn;          // divisible by 8 for our shapes
    int wg = blockIdx.x;
    wg = (wg & 7) * (nwg >> 3) + (wg >> 3);   // XCD swizzle (nwg % 8 == 0)
    const int bm = wg % nbm, bn = wg / nbm;
    const int brow = bm << 7, bcol = bn << 7;

    __shared__ u16 sA[128 * 32];
    __shared__ u16 sB[128 * 32];

    const int t = threadIdx.x;
    const int lane = t & 63, wid = t >> 6;
    const int wr = wid >> 1, wc = wid & 1;
    const int lr = lane & 15, lhi = lane >> 4;

    f32x4 acc[4][4] = {};

    for (int k0 = 0; k0 < K; k0 += 32) {
        __syncthreads();
        #pragma unroll
        for (int i = 0; i < 2; ++i) {
            const unsigned off = ((unsigned)t << 4) + ((unsigned)i << 12); // bytes
            const unsigned row = off >> 6;          // 64 B per row (32 bf16)
            const unsigned ce  = (off & 63) >> 1;   // elem col
            llds16(A  + (size_t)(brow + row) * K + (k0 + ce), sA + (off >> 1));
            llds16(Bw + (size_t)(bcol + row) * K + (k0 + ce), sB + (off >> 1));
        }
        __syncthreads();
        bf16x8 af[4], bfv[4];
        #pragma unroll
        for (int m = 0; m < 4; ++m)
            af[m] = *(const bf16x8*)(sA + ((wr*64 + m*16 + lr) * 32 + lhi*8));
        #pragma unroll
        for (int n = 0; n < 4; ++n)
            bfv[n] = *(const bf16x8*)(sB + ((wc*64 + n*16 + lr) * 32 + lhi*8));
        #pragma unroll
        for (int m = 0; m < 4; ++m)
            #pragma unroll
            for (int n = 0; n < 4; ++n)
                acc[m][n] = __builtin_amdgcn_mfma_f32_16x16x32_bf16(af[m], bfv[n], acc[m][n], 0, 0, 0);
    }

    #pragma unroll
    for (int m = 0; m < 4; ++m) {
        #pragma unroll
        for (int n = 0; n < 4; ++n) {
            const int col = bcol + wc*64 + n*16 + lr;
            const float bv = bias[col];
            #pragma unroll
            for (int j = 0; j < 4; ++j) {
                const int row = brow + wr*64 + m*16 + lhi*4 + j;
                C[(size_t)row * N + col] = acc[m][n][j] + bv;
            }
        }
    }
}

// ---------------- RoPE + pack Q (fold SCALE*kw[h]*log2e), bf16 [B][NH][S][64] ----------------
__global__ void rope_pack_q(const float* __restrict__ qkv, const float* __restrict__ tab,
                            const float* __restrict__ kw, u16* __restrict__ qb) {
    int idx = blockIdx.x * 256 + threadIdx.x;  // ((row)*32 + h)*32 + i
    int i = idx & 31;
    int h = (idx >> 5) & 31;
    int row = idx >> 10;                       // b*S + s
    int s = row & (S_LEN - 1);
    int b = row >> 11;
    float x1 = qkv[(size_t)row * QKVN + h*64 + i];
    float x2 = qkv[(size_t)row * QKVN + h*64 + i + 32];
    float cs = tab[s*32 + i], sn = tab[S_LEN*32 + s*32 + i];
    float sc = 0.125f * LOG2E * kw[h];
    size_t base = (((size_t)(b*NH + h)) * S_LEN + s) * 64;
    qb[base + i]      = f2bf((x1*cs - x2*sn) * sc);
    qb[base + i + 32] = f2bf((x2*cs + x1*sn) * sc);
}

// ---------------- RoPE + pack K, bf16 [B][NKV][S][64] ----------------
__global__ void rope_pack_k(const float* __restrict__ qkv, const float* __restrict__ tab,
                            u16* __restrict__ kb) {
    int idx = blockIdx.x * 256 + threadIdx.x;  // ((row)*8 + kvh)*32 + i
    int i = idx & 31;
    int kvh = (idx >> 5) & 7;
    int row = idx >> 8;
    int s = row & (S_LEN - 1);
    int b = row >> 11;
    float x1 = qkv[(size_t)row * QKVN + 2048 + kvh*64 + i];
    float x2 = qkv[(size_t)row * QKVN + 2048 + kvh*64 + i + 32];
    float cs = tab[s*32 + i], sn = tab[S_LEN*32 + s*32 + i];
    size_t base = (((size_t)(b*NKV + kvh)) * S_LEN + s) * 64;
    kb[base + i]      = f2bf(x1*cs - x2*sn);
    kb[base + i + 32] = f2bf(x2*cs + x1*sn);
}

// ---------------- pack V transposed: bf16 [B][NKV][64][S] via LDS tile ----------------
__global__ void pack_vt(const float* __restrict__ qkv, u16* __restrict__ vtb) {
    __shared__ float tile[64][65];
    const int st = blockIdx.x;          // s-tile
    const int bk = blockIdx.y;          // b*8 + kvh
    const int t = threadIdx.x;
    const int r = t >> 2, cg = (t & 3) << 4;
    const int b = bk >> 3, kvh = bk & 7;
    const float* src = qkv + ((size_t)(b*S_LEN + st*64 + r)) * QKVN + 2560 + kvh*64 + cg;
    #pragma unroll
    for (int j = 0; j < 16; ++j) tile[r][cg + j] = src[j];
    __syncthreads();
    const int d = t >> 2, sg = (t & 3) << 4;
    u16* dst = vtb + ((size_t)(bk*64 + d)) * S_LEN + st*64 + sg;
    #pragma unroll
    for (int j = 0; j < 16; ++j) dst[j] = f2bf(tile[sg + j][d]);
}

// ---------------- flash attention, causal, 4 waves x 16 q-rows, KV tile 64 ----------------
__global__ __launch_bounds__(256) void attn_fwd(
    const u16* __restrict__ Q,   // [B*NH][S][64], pre-scaled by SCALE*kw*log2e
    const u16* __restrict__ Kk,  // [B*NKV][S][64]
    const u16* __restrict__ Vt,  // [B*NKV][64][S]
    u16* __restrict__ O)         // [B*S][NH*64]
{
    __shared__ u16 sK[64 * 64];
    __shared__ u16 sV[64 * 64];
    __shared__ u16 sP[4][16 * 64];

    const int t = threadIdx.x;
    const int lane = t & 63, wid = t >> 6;
    const int lr = lane & 15, lhi = lane >> 4;
    const int qt = (int)gridDim.x - 1 - (int)blockIdx.x;   // long blocks first
    const int bh = blockIdx.y;
    const int b = bh >> 5, h = bh & 31;
    const int kvh = h >> 2;

    const u16* Kp = Kk + ((size_t)(b*NKV + kvh)) * S_LEN * 64;
    const u16* Vp = Vt + ((size_t)(b*NKV + kvh)) * 64 * S_LEN;

    // Q fragments (A operand): row = lr, k = lhi*8 (+32)
    const size_t qbase = (((size_t)bh) * S_LEN + qt*64 + wid*16) * 64;
    bf16x8 aq0 = *(const bf16x8*)&Q[qbase + (size_t)lr*64 + lhi*8];
    bf16x8 aq1 = *(const bf16x8*)&Q[qbase + (size_t)lr*64 + lhi*8 + 32];

    f32x4 accO[4] = {};
    float mrun[4], lrun[4];
    #pragma unroll
    for (int j = 0; j < 4; ++j) { mrun[j] = -INFINITY; lrun[j] = 0.f; }

    const int ntiles = qt + 1;
    for (int it = 0; it < ntiles; ++it) {
        const int kv0 = it * 64;
        __syncthreads();
        // stage K[kv][d] and Vt[d][kv] tiles; XOR-swizzle via pre-swizzled GLOBAL source
        #pragma unroll
        for (int i = 0; i < 2; ++i) {
            const unsigned off = ((unsigned)t << 4) + ((unsigned)i << 12); // bytes
            const unsigned row = off >> 7;                 // 128 B rows
            const unsigned cb  = off & 127;
            const unsigned scb = cb ^ ((row & 7) << 4);    // inverse-swizzled source chunk
            llds16(Kp + (size_t)(kv0 + row) * 64 + (scb >> 1), sK + (off >> 1));
            llds16(Vp + (size_t)row * S_LEN + kv0 + (scb >> 1), sV + (off >> 1));
        }
        __syncthreads();

        // S = Q K^T  (B operand from sK rows, swizzled reads)
        f32x4 s4[4];
        #pragma unroll
        for (int n = 0; n < 4; ++n) {
            const int krow = n*16 + lr;
            const char* base = (const char*)sK + krow * 128;
            bf16x8 bk0 = *(const bf16x8*)(base + (((unsigned)(lhi*16))      ^ ((krow & 7) << 4)));
            bf16x8 bk1 = *(const bf16x8*)(base + (((unsigned)(lhi*16 + 64)) ^ ((krow & 7) << 4)));
            f32x4 z = {};
            z = __builtin_amdgcn_mfma_f32_16x16x32_bf16(aq0, bk0, z, 0, 0, 0);
            z = __builtin_amdgcn_mfma_f32_16x16x32_bf16(aq1, bk1, z, 0, 0, 0);
            s4[n] = z;
        }

        // causal mask (only the diagonal tile)
        if (kv0 == qt * 64) {
            const int rbase = qt*64 + wid*16 + lhi*4;
            #pragma unroll
            for (int n = 0; n < 4; ++n) {
                const int colg = kv0 + n*16 + lr;
                #pragma unroll
                for (int j = 0; j < 4; ++j)
                    if (colg > rbase + j) s4[n][j] = -INFINITY;
            }
        }

        // online softmax (base-2 domain; scores already * log2e)
        float al[4];
        #pragma unroll
        for (int j = 0; j < 4; ++j) {
            float tm = fmaxf(fmaxf(s4[0][j], s4[1][j]), fmaxf(s4[2][j], s4[3][j]));
            #pragma unroll
            for (int o = 1; o < 16; o <<= 1) tm = fmaxf(tm, __shfl_xor(tm, o));
            const float mn = fmaxf(mrun[j], tm);
            al[j] = exp2f(mrun[j] - mn);
            mrun[j] = mn;
            float rs = 0.f;
            #pragma unroll
            for (int n = 0; n < 4; ++n) { float p = exp2f(s4[n][j] - mn); s4[n][j] = p; rs += p; }
            #pragma unroll
            for (int o = 1; o < 16; o <<= 1) rs += __shfl_xor(rs, o);
            lrun[j] = lrun[j] * al[j] + rs;
        }
        #pragma unroll
        for (int nd = 0; nd < 4; ++nd) {
            accO[nd][0] *= al[0]; accO[nd][1] *= al[1];
            accO[nd][2] *= al[2]; accO[nd][3] *= al[3];
        }

        // P -> per-wave swizzled LDS (rows = q, 128B rows), then read as A frags
        char* pbase = (char*)sP + wid * 2048;
        #pragma unroll
        for (int n = 0; n < 4; ++n)
            #pragma unroll
            for (int j = 0; j < 4; ++j) {
                const int pr = lhi*4 + j;
                const unsigned bcol = ((unsigned)((n*16 + lr) * 2)) ^ ((pr & 7) << 4);
                *(u16*)(pbase + pr*128 + bcol) = f2bf(s4[n][j]);
            }
        __asm__ volatile("s_waitcnt lgkmcnt(0)" ::: "memory");

        bf16x8 ap0 = *(const bf16x8*)(pbase + lr*128 + (((unsigned)(lhi*16))      ^ ((lr & 7) << 4)));
        bf16x8 ap1 = *(const bf16x8*)(pbase + lr*128 + (((unsigned)(lhi*16 + 64)) ^ ((lr & 7) << 4)));

        // O += P V   (B operand from sV rows = d, swizzled reads)
        #pragma unroll
        for (int nd = 0; nd < 4; ++nd) {
            const int vrow = nd*16 + lr;
            const char* vb = (const char*)sV + vrow * 128;
            bf16x8 bv0 = *(const bf16x8*)(vb + (((unsigned)(lhi*16))      ^ ((vrow & 7) << 4)));
            bf16x8 bv1 = *(const bf16x8*)(vb + (((unsigned)(lhi*16 + 64)) ^ ((vrow & 7) << 4)));
            accO[nd] = __builtin_amdgcn_mfma_f32_16x16x32_bf16(ap0, bv0, accO[nd], 0, 0, 0);
            accO[nd] = __builtin_amdgcn_mfma_f32_16x16x32_bf16(ap1, bv1, accO[nd], 0, 0, 0);
        }
    }

    // epilogue: normalize, write bf16 O[b*S + s][h*64 + d]
    #pragma unroll
    for (int j = 0; j < 4; ++j) {
        const float inv = 1.0f / lrun[j];
        const size_t orow = (size_t)b * S_LEN + qt*64 + wid*16 + lhi*4 + j;
        #pragma unroll
        for (int nd = 0; nd < 4; ++nd)
            O[orow * (NH*HD) + h*64 + nd*16 + lr] = f2bf(accO[nd][j] * inv);
    }
}

// ---------------- host launcher ----------------
extern "C" void kernel_launch(void* const* d_in, const int* in_sizes, int n_in,
                              void* d_out, int out_size, void* d_ws, size_t ws_size,
                              hipStream_t stream) {
    const float* x  = (const float*)d_in[0];
    const float* Wq = (const float*)d_in[1];
    const float* bq = (const float*)d_in[2];
    const float* Wk = (const float*)d_in[3];
    const float* bk = (const float*)d_in[4];
    const float* Wv = (const float*)d_in[5];
    const float* bv = (const float*)d_in[6];
    const float* Wo = (const float*)d_in[7];
    const float* bo = (const float*)d_in[8];
    const float* kw = (const float*)d_in[9];

    uint8_t* ws = (uint8_t*)d_ws;
    // phase-1 layout
    u16*   xb    = (u16*)(ws);                    // 16,777,216 B
    u16*   wqkvb = (u16*)(ws + 16777216);         // 12,582,912 B
    u16*   wob   = (u16*)(ws + 29360128);         //  8,388,608 B
    float* qkvf  = (float*)(ws + 37748736);       // 50,331,648 B
    float* bqkv  = (float*)(ws + 88080384);       //     12,288 B
    float* rtab  = (float*)(ws + 88092672);       //    524,288 B
    // phase-2 aliases (previous occupants dead by then)
    u16*   qb    = (u16*)(ws);                    // over xb
    u16*   kb    = (u16*)(ws + 16777216);         // over wqkvb
    u16*   vtb   = (u16*)(ws + 20971520);         // over wqkvb
    u16*   ob    = (u16*)(ws + 37748736);         // over qkvf

    // 1. convert to bf16
    cvt_f32_bf16<<<4096, 256, 0, stream>>>(x,  xb, 1048576);
    cvt_f32_bf16<<<2048, 256, 0, stream>>>(Wq, wqkvb, 524288);
    cvt_f32_bf16<<<512,  256, 0, stream>>>(Wk, wqkvb + (size_t)2048*2048, 131072);
    cvt_f32_bf16<<<512,  256, 0, stream>>>(Wv, wqkvb + (size_t)2560*2048, 131072);
    cvt_f32_bf16<<<2048, 256, 0, stream>>>(Wo, wob, 524288);
    build_bqkv<<<12, 256, 0, stream>>>(bq, bk, bv, bqkv);
    rope_table<<<256, 256, 0, stream>>>(rtab);

    // 2. QKV projection: [4096][3072] = xb @ wqkvb^T + bqkv
    gemm_bt<<<768, 256, 0, stream>>>(xb, wqkvb, bqkv, qkvf, NROWS, QKVN, HID);

    // 3. RoPE + pack into attention layouts
    rope_pack_q<<<16384, 256, 0, stream>>>(qkvf, rtab, kw, qb);
    rope_pack_k<<<4096, 256, 0, stream>>>(qkvf, rtab, kb);
    pack_vt<<<dim3(32, 16), 256, 0, stream>>>(qkvf, vtb);

    // 4. causal flash attention
    attn_fwd<<<dim3(32, BATCH*NH), 256, 0, stream>>>(qb, kb, vtb, ob);

    // 5. output projection: d_out = ob @ Wo^T + bo
    gemm_bt<<<512, 256, 0, stream>>>(ob, wob, bo, (float*)d_out, NROWS, HID, HID);

    (void)in_sizes; (void)n_in; (void)out_size; (void)ws_size;
}

// Round 2
// 255.572 us; speedup vs baseline: 1.5520x; 1.5520x over previous
//
#include <hip/hip_runtime.h>
#include <stdint.h>

#define S_LEN 2048
#define HID   2048
#define NH    32
#define NKV   8
#define HD    64
#define BATCH 2
#define NROWS (BATCH * S_LEN)      // 4096
#define QKVN  (NH*HD + 2*NKV*HD)   // 3072

typedef unsigned short u16;
typedef __bf16 bf16_t;
typedef bf16_t bf16x8 __attribute__((ext_vector_type(8)));
typedef float  f32x4  __attribute__((ext_vector_type(4)));
typedef float  f32x16 __attribute__((ext_vector_type(16)));
typedef u16    u16x8  __attribute__((ext_vector_type(8)));

#define LOG2E 1.4426950408889634f

__device__ __forceinline__ u16 f2bf(float f) {
    union { float f; uint32_t u; } v; v.f = f;
    uint32_t u = v.u;
    return (u16)((u + 0x7fffu + ((u >> 16) & 1u)) >> 16);
}

__device__ __forceinline__ unsigned cvtpk(float a, float b) {
    unsigned r;
    asm("v_cvt_pk_bf16_f32 %0, %1, %2" : "=v"(r) : "v"(a), "v"(b));
    return r;
}

__device__ __forceinline__ void llds16(const void* g, void* l) {
    __builtin_amdgcn_global_load_lds(
        (const __attribute__((address_space(1))) void*)g,
        (__attribute__((address_space(3))) void*)l,
        16, 0, 0);
}

// ---------------- f32 -> bf16 convert (16B vectorized) ----------------
__global__ void cvt_f32_bf16(const float* __restrict__ src, u16* __restrict__ dst, int n8) {
    int i = blockIdx.x * blockDim.x + threadIdx.x;
    if (i >= n8) return;
    const float4* s = (const float4*)src;
    float4 a = s[2*(size_t)i], b = s[2*(size_t)i + 1];
    u16x8 r;
    r[0]=f2bf(a.x); r[1]=f2bf(a.y); r[2]=f2bf(a.z); r[3]=f2bf(a.w);
    r[4]=f2bf(b.x); r[5]=f2bf(b.y); r[6]=f2bf(b.z); r[7]=f2bf(b.w);
    *(u16x8*)(dst + 8*(size_t)i) = r;
}

// ---------------- concat bias (bq|bk|bv) ----------------
__global__ void build_bqkv(const float* __restrict__ bq, const float* __restrict__ bk,
                           const float* __restrict__ bv, float* __restrict__ bqkv) {
    int i = blockIdx.x * 256 + threadIdx.x;
    if (i >= QKVN) return;
    bqkv[i] = (i < 2048) ? bq[i] : (i < 2560 ? bk[i - 2048] : bv[i - 2560]);
}

// ---------------- RoPE table: cos at [0:65536), sin at [65536:131072) ----------------
__global__ void rope_table(float* __restrict__ tab) {
    int idx = blockIdx.x * 256 + threadIdx.x;   // s*32 + i
    if (idx >= S_LEN * 32) return;
    int i = idx & 31, s = idx >> 5;
    float invf = exp2f(-(float)i * (13.287712379549449f / 32.0f));
    float ang = (float)s * invf;
    float sn, cs;
    sincosf(ang, &sn, &cs);
    tab[idx] = cs;
    tab[S_LEN*32 + idx] = sn;
}

// ---------------- bf16 GEMM, C[M][N] = A[M][K] * Bw[N][K]^T + bias[n] (m97 structure) ----------------
__global__ __launch_bounds__(256) void gemm_bt(
    const u16* __restrict__ A, const u16* __restrict__ Bw,
    const float* __restrict__ bias, float* __restrict__ C,
    int M, int N, int K)
{
    const int nbm = M >> 7, nbn = N >> 7;
    const int nwg = nbm * nbn;
    int wg = blockIdx.x;
    wg = (wg & 7) * (nwg >> 3) + (wg >> 3);   // XCD swizzle (nwg % 8 == 0)
    const int bm = wg % nbm, bn = wg / nbm;
    const int brow = bm << 7, bcol = bn << 7;

    __shared__ u16 sA[128 * 32];
    __shared__ u16 sB[128 * 32];

    const int t = threadIdx.x;
    const int lane = t & 63, wid = t >> 6;
    const int wr = wid >> 1, wc = wid & 1;
    const int lr = lane & 15, lhi = lane >> 4;

    f32x4 acc[4][4] = {};

    for (int k0 = 0; k0 < K; k0 += 32) {
        __syncthreads();
        #pragma unroll
        for (int i = 0; i < 2; ++i) {
            const unsigned off = ((unsigned)t << 4) + ((unsigned)i << 12); // bytes
            const unsigned row = off >> 6;          // 64 B per row (32 bf16)
            const unsigned ce  = (off & 63) >> 1;   // elem col
            llds16(A  + (size_t)(brow + row) * K + (k0 + ce), sA + (off >> 1));
            llds16(Bw + (size_t)(bcol + row) * K + (k0 + ce), sB + (off >> 1));
        }
        __syncthreads();
        bf16x8 af[4], bfv[4];
        #pragma unroll
        for (int m = 0; m < 4; ++m)
            af[m] = *(const bf16x8*)(sA + ((wr*64 + m*16 + lr) * 32 + lhi*8));
        #pragma unroll
        for (int n = 0; n < 4; ++n)
            bfv[n] = *(const bf16x8*)(sB + ((wc*64 + n*16 + lr) * 32 + lhi*8));
        #pragma unroll
        for (int m = 0; m < 4; ++m)
            #pragma unroll
            for (int n = 0; n < 4; ++n)
                acc[m][n] = __builtin_amdgcn_mfma_f32_16x16x32_bf16(af[m], bfv[n], acc[m][n], 0, 0, 0);
    }

    #pragma unroll
    for (int m = 0; m < 4; ++m) {
        #pragma unroll
        for (int n = 0; n < 4; ++n) {
            const int col = bcol + wc*64 + n*16 + lr;
            const float bv = bias[col];
            #pragma unroll
            for (int j = 0; j < 4; ++j) {
                const int row = brow + wr*64 + m*16 + lhi*4 + j;
                C[(size_t)row * N + col] = acc[m][n][j] + bv;
            }
        }
    }
}

// ---------------- RoPE + pack Q (fold SCALE*kw[h]*log2e), bf16 [B][NH][S][64] ----------------
__global__ void rope_pack_q(const float* __restrict__ qkv, const float* __restrict__ tab,
                            const float* __restrict__ kw, u16* __restrict__ qb) {
    int idx = blockIdx.x * 256 + threadIdx.x;  // ((row)*32 + h)*32 + i
    int i = idx & 31;
    int h = (idx >> 5) & 31;
    int row = idx >> 10;                       // b*S + s
    int s = row & (S_LEN - 1);
    int b = row >> 11;
    float x1 = qkv[(size_t)row * QKVN + h*64 + i];
    float x2 = qkv[(size_t)row * QKVN + h*64 + i + 32];
    float cs = tab[s*32 + i], sn = tab[S_LEN*32 + s*32 + i];
    float sc = 0.125f * LOG2E * kw[h];
    size_t base = (((size_t)(b*NH + h)) * S_LEN + s) * 64;
    qb[base + i]      = f2bf((x1*cs - x2*sn) * sc);
    qb[base + i + 32] = f2bf((x2*cs + x1*sn) * sc);
}

// ---------------- RoPE + pack K, bf16 [B][NKV][S][64] ----------------
__global__ void rope_pack_k(const float* __restrict__ qkv, const float* __restrict__ tab,
                            u16* __restrict__ kb) {
    int idx = blockIdx.x * 256 + threadIdx.x;  // ((row)*8 + kvh)*32 + i
    int i = idx & 31;
    int kvh = (idx >> 5) & 7;
    int row = idx >> 8;
    int s = row & (S_LEN - 1);
    int b = row >> 11;
    float x1 = qkv[(size_t)row * QKVN + 2048 + kvh*64 + i];
    float x2 = qkv[(size_t)row * QKVN + 2048 + kvh*64 + i + 32];
    float cs = tab[s*32 + i], sn = tab[S_LEN*32 + s*32 + i];
    size_t base = (((size_t)(b*NKV + kvh)) * S_LEN + s) * 64;
    kb[base + i]      = f2bf(x1*cs - x2*sn);
    kb[base + i + 32] = f2bf(x2*cs + x1*sn);
}

// ---------------- pack V transposed: bf16 [B][NKV][64][S] via LDS tile ----------------
__global__ void pack_vt(const float* __restrict__ qkv, u16* __restrict__ vtb) {
    __shared__ float tile[64][65];
    const int st = blockIdx.x;          // s-tile
    const int bk = blockIdx.y;          // b*8 + kvh
    const int t = threadIdx.x;
    const int r = t >> 2, cg = (t & 3) << 4;
    const int b = bk >> 3, kvh = bk & 7;
    const float* src = qkv + ((size_t)(b*S_LEN + st*64 + r)) * QKVN + 2560 + kvh*64 + cg;
    #pragma unroll
    for (int j = 0; j < 16; ++j) tile[r][cg + j] = src[j];
    __syncthreads();
    const int d = t >> 2, sg = (t & 3) << 4;
    u16* dst = vtb + ((size_t)(bk*64 + d)) * S_LEN + st*64 + sg;
    #pragma unroll
    for (int j = 0; j < 16; ++j) dst[j] = f2bf(tile[sg + j][d]);
}

// ---------------- flash attention: 8 waves x 32 q-rows, swapped 32x32 MFMA ----------------
// Q pre-scaled by SCALE*kw*log2e. Per wave: QK^T as mfma(K,Q) -> P lane-local
// (col=lane&31=q, row=crow(r,hi)=kv). PV as mfma(Vt,P^T) -> O col=lane&31=q.
__global__ __launch_bounds__(512, 4) void attn_fwd(
    const u16* __restrict__ Q,   // [B*NH][S][64]
    const u16* __restrict__ Kk,  // [B*NKV][S][64]
    const u16* __restrict__ Vt,  // [B*NKV][64][S]
    u16* __restrict__ O)         // [B*S][NH*64]
{
    __shared__ u16 sK[2][64 * 64];
    __shared__ u16 sV[2][64 * 64];

    const int t = threadIdx.x;
    const int lane = t & 63, wid = t >> 6;
    const int hi = lane >> 5, lq = lane & 31;
    const int bid = blockIdx.x;
    const int qb = 7 - (bid >> 6);          // long blocks first
    const int bh = bid & 63;                // same bh -> bid stride 64 -> same XCD
    const int b = bh >> 5, h = bh & 31;
    const int kvh = h >> 2;

    const u16* Kp = Kk + ((size_t)(b*NKV + kvh)) * (S_LEN * 64);
    const u16* Vp = Vt + ((size_t)(b*NKV + kvh)) * (64 * S_LEN);

    const int q0w = qb*256 + wid*32;        // wave's first q row
    const int qg  = q0w + lq;               // this lane's q row

    // Q B-operand frags: col=q=lq, k(d) = 16*kd + 8*hi + j
    const u16* Qrow = Q + (((size_t)bh) * S_LEN + qg) * 64 + 8*hi;
    bf16x8 qf[4];
    #pragma unroll
    for (int kd = 0; kd < 4; ++kd)
        qf[kd] = *(const bf16x8*)(Qrow + 16*kd);

    f32x16 accO0 = {}, accO1 = {};          // O[q=lq][d = crow(r,hi) + 32*dm]
    float m_run = -INFINITY, l_run = 0.f;

    const int ntB = 4*qb + 4;
    const int tmax_w = (q0w + 31) >> 6;     // last tile this wave needs

    // prologue: stage tile 0 into buf 0 (pre-swizzled source, linear LDS dest)
    {
        const unsigned row = t >> 3, cb = (t & 7) << 4;
        const unsigned scb = cb ^ ((row & 7) << 4);
        llds16(Kp + (size_t)row * 64 + (scb >> 1), &sK[0][0] + t*8);
        llds16(Vp + (size_t)row * S_LEN + (scb >> 1), &sV[0][0] + t*8);
    }
    asm volatile("s_waitcnt vmcnt(0)" ::: "memory");
    __syncthreads();

    for (int tt = 0; tt < ntB; ++tt) {
        const int buf = tt & 1;
        const int kv0 = tt * 64;
        if (tt + 1 < ntB) {                 // stage next tile into other buffer
            const int kvn = kv0 + 64;
            const unsigned row = t >> 3, cb = (t & 7) << 4;
            const unsigned scb = cb ^ ((row & 7) << 4);
            llds16(Kp + (size_t)(kvn + row) * 64 + (scb >> 1), &sK[buf^1][0] + t*8);
            llds16(Vp + (size_t)row * S_LEN + kvn + (scb >> 1), &sV[buf^1][0] + t*8);
        }
        if (tt <= tmax_w) {
            // ---- QK^T (swapped): s[m] covers kv = kv0 + 32m + crow(r,hi)
            f32x16 s0 = {}, s1 = {};
            #pragma unroll
            for (int kd = 0; kd < 4; ++kd) {
                const unsigned bc = ((unsigned)(32*kd + 16*hi)) ^ ((lq & 7) << 4);
                bf16x8 k0 = *(const bf16x8*)((const char*)&sK[buf][0] + lq*128 + bc);
                bf16x8 k1 = *(const bf16x8*)((const char*)&sK[buf][0] + (32 + lq)*128 + bc);
                s0 = __builtin_amdgcn_mfma_f32_32x32x16_bf16(k0, qf[kd], s0, 0, 0, 0);
                s1 = __builtin_amdgcn_mfma_f32_32x32x16_bf16(k1, qf[kd], s1, 0, 0, 0);
            }
            // ---- causal mask (diagonal-overlapping tiles only)
            if (kv0 + 63 > q0w) {
                #pragma unroll
                for (int r = 0; r < 16; ++r) {
                    const int kvg = kv0 + (r & 3) + 8*(r >> 2) + 4*hi;
                    if (kvg > qg)      s0[r] = -INFINITY;
                    if (kvg + 32 > qg) s1[r] = -INFINITY;
                }
            }
            // ---- online softmax: row owned by lane pair (lq, lq+32)
            float tm = fmaxf(s0[0], s1[0]);
            #pragma unroll
            for (int r = 1; r < 16; ++r) tm = fmaxf(tm, fmaxf(s0[r], s1[r]));
            tm = fmaxf(tm, __shfl_xor(tm, 32));
            const float mn = fmaxf(m_run, tm);
            const float al = exp2f(m_run - mn);
            m_run = mn;
            float rs = 0.f;
            #pragma unroll
            for (int r = 0; r < 16; ++r) {
                s0[r] = exp2f(s0[r] - mn);
                s1[r] = exp2f(s1[r] - mn);
                rs += s0[r] + s1[r];
            }
            rs += __shfl_xor(rs, 32);
            l_run = l_run * al + rs;
            #pragma unroll
            for (int r = 0; r < 16; ++r) { accO0[r] *= al; accO1[r] *= al; }

            // ---- pack P to bf16 words: x=(r2=0), y=(r2=1) halves per ks
            unsigned xw[4][2], yw[4][2];
            #pragma unroll
            for (int ks = 0; ks < 4; ++ks) {
                const f32x16& e = (ks & 2) ? s1 : s0;
                const int rb = (ks & 1) * 8;
                xw[ks][0] = cvtpk(e[rb + 0], e[rb + 1]);
                xw[ks][1] = cvtpk(e[rb + 2], e[rb + 3]);
                yw[ks][0] = cvtpk(e[rb + 4], e[rb + 5]);
                yw[ks][1] = cvtpk(e[rb + 6], e[rb + 7]);
            }
            // ---- PV: pb[ks] = P^T B-frag (k = kv = 16ks + 8hi + j) via pair exchange
            #pragma unroll
            for (int ks = 0; ks < 4; ++ks) {
                const unsigned sx0 = (unsigned)__shfl_xor((int)xw[ks][0], 32);
                const unsigned sx1 = (unsigned)__shfl_xor((int)xw[ks][1], 32);
                const unsigned sy0 = (unsigned)__shfl_xor((int)yw[ks][0], 32);
                const unsigned sy1 = (unsigned)__shfl_xor((int)yw[ks][1], 32);
                union { unsigned u[4]; bf16x8 v; } pb;
                pb.u[0] = hi ? sy0 : xw[ks][0];
                pb.u[1] = hi ? sy1 : xw[ks][1];
                pb.u[2] = hi ? yw[ks][0] : sx0;
                pb.u[3] = hi ? yw[ks][1] : sx1;
                const unsigned bc = ((unsigned)(32*ks + 16*hi)) ^ ((lq & 7) << 4);
                bf16x8 v0 = *(const bf16x8*)((const char*)&sV[buf][0] + lq*128 + bc);
                bf16x8 v1 = *(const bf16x8*)((const char*)&sV[buf][0] + (32 + lq)*128 + bc);
                accO0 = __builtin_amdgcn_mfma_f32_32x32x16_bf16(v0, pb.v, accO0, 0, 0, 0);
                accO1 = __builtin_amdgcn_mfma_f32_32x32x16_bf16(v1, pb.v, accO1, 0, 0, 0);
            }
        }
        asm volatile("s_waitcnt vmcnt(0)" ::: "memory");
        __syncthreads();
    }

    // ---- epilogue: normalize, write O[q][h*64 + d], d = 32dm + 8g + 4hi + (0..3)
    const float inv = 1.0f / l_run;
    u16* orow = O + (((size_t)(b * S_LEN) + q0w + lq)) * (NH*HD) + h*64;
    #pragma unroll
    for (int g = 0; g < 4; ++g) {
        uint2 w0, w1;
        w0.x = cvtpk(accO0[4*g + 0] * inv, accO0[4*g + 1] * inv);
        w0.y = cvtpk(accO0[4*g + 2] * inv, accO0[4*g + 3] * inv);
        *(uint2*)(orow + 8*g + 4*hi) = w0;
        w1.x = cvtpk(accO1[4*g + 0] * inv, accO1[4*g + 1] * inv);
        w1.y = cvtpk(accO1[4*g + 2] * inv, accO1[4*g + 3] * inv);
        *(uint2*)(orow + 32 + 8*g + 4*hi) = w1;
    }
}

// ---------------- host launcher ----------------
extern "C" void kernel_launch(void* const* d_in, const int* in_sizes, int n_in,
                              void* d_out, int out_size, void* d_ws, size_t ws_size,
                              hipStream_t stream) {
    const float* x  = (const float*)d_in[0];
    const float* Wq = (const float*)d_in[1];
    const float* bq = (const float*)d_in[2];
    const float* Wk = (const float*)d_in[3];
    const float* bk = (const float*)d_in[4];
    const float* Wv = (const float*)d_in[5];
    const float* bv = (const float*)d_in[6];
    const float* Wo = (const float*)d_in[7];
    const float* bo = (const float*)d_in[8];
    const float* kw = (const float*)d_in[9];

    uint8_t* ws = (uint8_t*)d_ws;
    // phase-1 layout
    u16*   xb    = (u16*)(ws);                    // 16,777,216 B
    u16*   wqkvb = (u16*)(ws + 16777216);         // 12,582,912 B
    u16*   wob   = (u16*)(ws + 29360128);         //  8,388,608 B
    float* qkvf  = (float*)(ws + 37748736);       // 50,331,648 B
    float* bqkv  = (float*)(ws + 88080384);       //     12,288 B
    float* rtab  = (float*)(ws + 88092672);       //    524,288 B
    // phase-2 aliases (previous occupants dead by then)
    u16*   qbp   = (u16*)(ws);                    // over xb
    u16*   kb    = (u16*)(ws + 16777216);         // over wqkvb
    u16*   vtb   = (u16*)(ws + 20971520);         // over wqkvb
    u16*   ob    = (u16*)(ws + 37748736);         // over qkvf

    // 1. convert to bf16
    cvt_f32_bf16<<<4096, 256, 0, stream>>>(x,  xb, 1048576);
    cvt_f32_bf16<<<2048, 256, 0, stream>>>(Wq, wqkvb, 524288);
    cvt_f32_bf16<<<512,  256, 0, stream>>>(Wk, wqkvb + (size_t)2048*2048, 131072);
    cvt_f32_bf16<<<512,  256, 0, stream>>>(Wv, wqkvb + (size_t)2560*2048, 131072);
    cvt_f32_bf16<<<2048, 256, 0, stream>>>(Wo, wob, 524288);
    build_bqkv<<<12, 256, 0, stream>>>(bq, bk, bv, bqkv);
    rope_table<<<256, 256, 0, stream>>>(rtab);

    // 2. QKV projection: [4096][3072] = xb @ wqkvb^T + bqkv
    gemm_bt<<<768, 256, 0, stream>>>(xb, wqkvb, bqkv, qkvf, NROWS, QKVN, HID);

    // 3. RoPE + pack into attention layouts
    rope_pack_q<<<16384, 256, 0, stream>>>(qkvf, rtab, kw, qbp);
    rope_pack_k<<<4096, 256, 0, stream>>>(qkvf, rtab, kb);
    pack_vt<<<dim3(32, 16), 256, 0, stream>>>(qkvf, vtb);

    // 4. causal flash attention: 512 blocks (8 q-tiles x 64 bh), 8 waves each
    attn_fwd<<<dim3(512), dim3(512), 0, stream>>>(qbp, kb, vtb, ob);

    // 5. output projection: d_out = ob @ Wo^T + bo
    gemm_bt<<<512, 256, 0, stream>>>(ob, wob, bo, (float*)d_out, NROWS, HID, HID);

    (void)in_sizes; (void)n_in; (void)out_size; (void)ws_size;
}

// Round 4
// 238.356 us; speedup vs baseline: 1.6641x; 1.0722x over previous
//
#include <hip/hip_runtime.h>
#include <stdint.h>

#define S_LEN 2048
#define HID   2048
#define NH    32
#define NKV   8
#define HD    64
#define BATCH 2
#define NROWS (BATCH * S_LEN)      // 4096
#define QKVN  (NH*HD + 2*NKV*HD)   // 3072

typedef unsigned short u16;
typedef __bf16 bf16_t;
typedef bf16_t bf16x8 __attribute__((ext_vector_type(8)));
typedef float  f32x4  __attribute__((ext_vector_type(4)));
typedef float  f32x16 __attribute__((ext_vector_type(16)));
typedef u16    u16x8  __attribute__((ext_vector_type(8)));

#define LOG2E 1.4426950408889634f

__device__ __forceinline__ u16 f2bf(float f) {
    union { float f; uint32_t u; } v; v.f = f;
    uint32_t u = v.u;
    return (u16)((u + 0x7fffu + ((u >> 16) & 1u)) >> 16);
}

__device__ __forceinline__ unsigned cvtpk(float a, float b) {
    unsigned r;
    asm("v_cvt_pk_bf16_f32 %0, %1, %2" : "=v"(r) : "v"(a), "v"(b));
    return r;
}

__device__ __forceinline__ void llds16(const void* g, void* l) {
    __builtin_amdgcn_global_load_lds(
        (const __attribute__((address_space(1))) void*)g,
        (__attribute__((address_space(3))) void*)l,
        16, 0, 0);
}

// ---------------- fused f32 -> bf16 convert for all 5 tensors ----------------
__global__ void cvt_all(const float* __restrict__ x, const float* __restrict__ wq,
                        const float* __restrict__ wk, const float* __restrict__ wv,
                        const float* __restrict__ wo,
                        u16* __restrict__ xb, u16* __restrict__ wqkvb, u16* __restrict__ wob) {
    int e = blockIdx.x * 256 + threadIdx.x;   // 8-elem group index
    const float* s; u16* d; int o;
    if (e < 1048576)      { s = x;  d = xb;                 o = e; }
    else if (e < 1572864) { s = wq; d = wqkvb;              o = e - 1048576; }
    else if (e < 1703936) { s = wk; d = wqkvb + 2048*2048;  o = e - 1572864; }
    else if (e < 1835008) { s = wv; d = wqkvb + 2560*2048;  o = e - 1703936; }
    else                  { s = wo; d = wob;                o = e - 1835008; }
    const float4* sp = (const float4*)s;
    float4 a = sp[2*(size_t)o], b = sp[2*(size_t)o + 1];
    u16x8 r;
    r[0]=f2bf(a.x); r[1]=f2bf(a.y); r[2]=f2bf(a.z); r[3]=f2bf(a.w);
    r[4]=f2bf(b.x); r[5]=f2bf(b.y); r[6]=f2bf(b.z); r[7]=f2bf(b.w);
    *(u16x8*)(d + 8*(size_t)o) = r;
}

// ---------------- concat bias (bq|bk|bv) ----------------
__global__ void build_bqkv(const float* __restrict__ bq, const float* __restrict__ bk,
                           const float* __restrict__ bv, float* __restrict__ bqkv) {
    int i = blockIdx.x * 256 + threadIdx.x;
    if (i >= QKVN) return;
    bqkv[i] = (i < 2048) ? bq[i] : (i < 2560 ? bk[i - 2048] : bv[i - 2560]);
}

// ---------------- RoPE table: cos at [0:65536), sin at [65536:131072) ----------------
__global__ void rope_table(float* __restrict__ tab) {
    int idx = blockIdx.x * 256 + threadIdx.x;   // s*32 + i
    if (idx >= S_LEN * 32) return;
    int i = idx & 31, s = idx >> 5;
    float invf = exp2f(-(float)i * (13.287712379549449f / 32.0f));
    float ang = (float)s * invf;
    float sn, cs;
    sincosf(ang, &sn, &cs);
    tab[idx] = cs;
    tab[S_LEN*32 + idx] = sn;
}

// ---------------- bf16 GEMM, C[M][N] = A[M][K] * Bw[N][K]^T + bias[n] (m97 structure) ----------------
__global__ __launch_bounds__(256) void gemm_bt(
    const u16* __restrict__ A, const u16* __restrict__ Bw,
    const float* __restrict__ bias, float* __restrict__ C,
    int M, int N, int K)
{
    const int nbm = M >> 7, nbn = N >> 7;
    const int nwg = nbm * nbn;
    int wg = blockIdx.x;
    wg = (wg & 7) * (nwg >> 3) + (wg >> 3);   // XCD swizzle (nwg % 8 == 0)
    const int bm = wg % nbm, bn = wg / nbm;
    const int brow = bm << 7, bcol = bn << 7;

    __shared__ u16 sA[128 * 32];
    __shared__ u16 sB[128 * 32];

    const int t = threadIdx.x;
    const int lane = t & 63, wid = t >> 6;
    const int wr = wid >> 1, wc = wid & 1;
    const int lr = lane & 15, lhi = lane >> 4;

    f32x4 acc[4][4] = {};

    for (int k0 = 0; k0 < K; k0 += 32) {
        __syncthreads();
        #pragma unroll
        for (int i = 0; i < 2; ++i) {
            const unsigned off = ((unsigned)t << 4) + ((unsigned)i << 12); // bytes
            const unsigned row = off >> 6;          // 64 B per row (32 bf16)
            const unsigned ce  = (off & 63) >> 1;   // elem col
            llds16(A  + (size_t)(brow + row) * K + (k0 + ce), sA + (off >> 1));
            llds16(Bw + (size_t)(bcol + row) * K + (k0 + ce), sB + (off >> 1));
        }
        __syncthreads();
        bf16x8 af[4], bfv[4];
        #pragma unroll
        for (int m = 0; m < 4; ++m)
            af[m] = *(const bf16x8*)(sA + ((wr*64 + m*16 + lr) * 32 + lhi*8));
        #pragma unroll
        for (int n = 0; n < 4; ++n)
            bfv[n] = *(const bf16x8*)(sB + ((wc*64 + n*16 + lr) * 32 + lhi*8));
        #pragma unroll
        for (int m = 0; m < 4; ++m)
            #pragma unroll
            for (int n = 0; n < 4; ++n)
                acc[m][n] = __builtin_amdgcn_mfma_f32_16x16x32_bf16(af[m], bfv[n], acc[m][n], 0, 0, 0);
    }

    #pragma unroll
    for (int m = 0; m < 4; ++m) {
        #pragma unroll
        for (int n = 0; n < 4; ++n) {
            const int col = bcol + wc*64 + n*16 + lr;
            const float bv = bias[col];
            #pragma unroll
            for (int j = 0; j < 4; ++j) {
                const int row = brow + wr*64 + m*16 + lhi*4 + j;
                C[(size_t)row * N + col] = acc[m][n][j] + bv;
            }
        }
    }
}

// ---------------- RoPE + pack K, bf16 [B][NKV][S][64] ----------------
__global__ void rope_pack_k(const float* __restrict__ qkv, const float* __restrict__ tab,
                            u16* __restrict__ kb) {
    int idx = blockIdx.x * 256 + threadIdx.x;  // ((row)*8 + kvh)*32 + i
    int i = idx & 31;
    int kvh = (idx >> 5) & 7;
    int row = idx >> 8;
    int s = row & (S_LEN - 1);
    int b = row >> 11;
    float x1 = qkv[(size_t)row * QKVN + 2048 + kvh*64 + i];
    float x2 = qkv[(size_t)row * QKVN + 2048 + kvh*64 + i + 32];
    float cs = tab[s*32 + i], sn = tab[S_LEN*32 + s*32 + i];
    size_t base = (((size_t)(b*NKV + kvh)) * S_LEN + s) * 64;
    kb[base + i]      = f2bf(x1*cs - x2*sn);
    kb[base + i + 32] = f2bf(x2*cs + x1*sn);
}

// ---------------- pack V transposed: bf16 [B][NKV][64][S] via LDS tile ----------------
__global__ void pack_vt(const float* __restrict__ qkv, u16* __restrict__ vtb) {
    __shared__ float tile[64][65];
    const int st = blockIdx.x;          // s-tile
    const int bk = blockIdx.y;          // b*8 + kvh
    const int t = threadIdx.x;
    const int r = t >> 2, cg = (t & 3) << 4;
    const int b = bk >> 3, kvh = bk & 7;
    const float* src = qkv + ((size_t)(b*S_LEN + st*64 + r)) * QKVN + 2560 + kvh*64 + cg;
    #pragma unroll
    for (int j = 0; j < 16; ++j) tile[r][cg + j] = src[j];
    __syncthreads();
    const int d = t >> 2, sg = (t & 3) << 4;
    u16* dst = vtb + ((size_t)(bk*64 + d)) * S_LEN + st*64 + sg;
    #pragma unroll
    for (int j = 0; j < 16; ++j) dst[j] = f2bf(tile[sg + j][d]);
}

// ---------------- flash attention: 8 waves x 32 q-rows, swapped 32x32 MFMA ----------------
// Q-RoPE fused in prologue (reads f32 qkv). Per wave: QK^T as mfma(K,Q) -> P lane-local;
// PV as mfma(Vt,P^T) -> O col=lane&31=q. Half-wave exchange via shfl_xor(.,32) (proven R2).
__global__ __launch_bounds__(512, 4) void attn_fwd(
    const float* __restrict__ Qf,   // qkvf [B*S][3072]
    const float* __restrict__ rtab,
    const float* __restrict__ kw,
    const u16* __restrict__ Kk,     // [B*NKV][S][64]
    const u16* __restrict__ Vt,     // [B*NKV][64][S]
    u16* __restrict__ O)            // [B*S][NH*64]
{
    __shared__ u16 sK[2][64 * 64];
    __shared__ u16 sV[2][64 * 64];

    const int t = threadIdx.x;
    const int lane = t & 63, wid = t >> 6;
    const int hi = lane >> 5, lq = lane & 31;
    const int bid = blockIdx.x;
    // balanced pairing: bid & bid+256 qb's sum to 7 (36 tiles per CU pair)
    const int qb = (bid < 256) ? (7 - (bid >> 6)) : ((bid >> 6) - 4);
    const int bh = bid & 63;                // same bh -> bid stride 64 -> same XCD
    const int b = bh >> 5, h = bh & 31;
    const int kvh = h >> 2;

    const u16* Kp = Kk + ((size_t)(b*NKV + kvh)) * (S_LEN * 64);
    const u16* Vp = Vt + ((size_t)(b*NKV + kvh)) * (64 * S_LEN);

    const int q0w = qb*256 + wid*32;        // wave's first q row
    const int qg  = q0w + lq;               // this lane's q row (s index)

    // ---- Q fragments with fused RoPE + fold SCALE*kw*log2e ----
    const float sc = 0.125f * LOG2E * kw[h];
    const float* qsrc = Qf + ((size_t)(b*S_LEN + qg)) * QKVN + h*64;
    const float* ct = rtab + qg*32;
    const float* st = rtab + 65536 + qg*32;
    bf16x8 qf[4];
    #pragma unroll
    for (int kd = 0; kd < 2; ++kd) {
        const int i0 = 16*kd + 8*hi;
        union { u16 u[8]; bf16x8 v; } w1, w2;
        #pragma unroll
        for (int j = 0; j < 8; ++j) {
            float a  = qsrc[i0 + j];
            float b2 = qsrc[i0 + j + 32];
            float cs = ct[i0 + j], sn = st[i0 + j];
            w1.u[j] = f2bf((a*cs - b2*sn) * sc);
            w2.u[j] = f2bf((b2*cs + a*sn) * sc);
        }
        qf[kd]     = w1.v;
        qf[kd + 2] = w2.v;
    }

    f32x16 accO0 = {}, accO1 = {};          // O[q=lq][d = crow(r,hi) + 32*dm]
    float m_run = -INFINITY, l_run = 0.f;

    const int ntB = 4*qb + 4;
    const int tmax_w = (q0w + 31) >> 6;     // last tile this wave needs

    // prologue: stage tile 0 into buf 0 (pre-swizzled source, linear LDS dest)
    {
        const unsigned row = t >> 3, cb = (t & 7) << 4;
        const unsigned scb = cb ^ ((row & 7) << 4);
        llds16(Kp + (size_t)row * 64 + (scb >> 1), &sK[0][0] + t*8);
        llds16(Vp + (size_t)row * S_LEN + (scb >> 1), &sV[0][0] + t*8);
    }
    asm volatile("s_waitcnt vmcnt(0)" ::: "memory");
    __syncthreads();

    for (int tt = 0; tt < ntB; ++tt) {
        const int buf = tt & 1;
        const int kv0 = tt * 64;
        if (tt + 1 < ntB) {                 // stage next tile into other buffer
            const int kvn = kv0 + 64;
            const unsigned row = t >> 3, cb = (t & 7) << 4;
            const unsigned scb = cb ^ ((row & 7) << 4);
            llds16(Kp + (size_t)(kvn + row) * 64 + (scb >> 1), &sK[buf^1][0] + t*8);
            llds16(Vp + (size_t)row * S_LEN + kvn + (scb >> 1), &sV[buf^1][0] + t*8);
        }
        if (tt <= tmax_w) {
            // ---- QK^T (swapped): s[m] covers kv = kv0 + 32m + crow(r,hi)
            f32x16 s0 = {}, s1 = {};
            #pragma unroll
            for (int kd = 0; kd < 4; ++kd) {
                const unsigned bc = ((unsigned)(32*kd + 16*hi)) ^ ((lq & 7) << 4);
                bf16x8 k0 = *(const bf16x8*)((const char*)&sK[buf][0] + lq*128 + bc);
                bf16x8 k1 = *(const bf16x8*)((const char*)&sK[buf][0] + (32 + lq)*128 + bc);
                s0 = __builtin_amdgcn_mfma_f32_32x32x16_bf16(k0, qf[kd], s0, 0, 0, 0);
                s1 = __builtin_amdgcn_mfma_f32_32x32x16_bf16(k1, qf[kd], s1, 0, 0, 0);
            }
            // ---- causal mask (diagonal-overlapping tiles only)
            if (kv0 + 63 > q0w) {
                #pragma unroll
                for (int r = 0; r < 16; ++r) {
                    const int kvg = kv0 + (r & 3) + 8*(r >> 2) + 4*hi;
                    if (kvg > qg)      s0[r] = -INFINITY;
                    if (kvg + 32 > qg) s1[r] = -INFINITY;
                }
            }
            // ---- tile max (tree, depth 5) + half-wave combine (shfl_xor, proven)
            float mx[8];
            #pragma unroll
            for (int r = 0; r < 8; ++r)
                mx[r] = fmaxf(fmaxf(s0[r], s0[r+8]), fmaxf(s1[r], s1[r+8]));
            float tm = fmaxf(fmaxf(fmaxf(mx[0], mx[1]), fmaxf(mx[2], mx[3])),
                             fmaxf(fmaxf(mx[4], mx[5]), fmaxf(mx[6], mx[7])));
            tm = fmaxf(tm, __shfl_xor(tm, 32));
            // ---- defer-max (T13): only rescale when tile max outgrew m_run by >8
            if (!__all(tm <= m_run + 8.0f)) {
                const float mn = fmaxf(m_run, tm);
                const float al = exp2f(m_run - mn);
                m_run = mn;
                l_run *= al;
                #pragma unroll
                for (int r = 0; r < 16; ++r) { accO0[r] *= al; accO1[r] *= al; }
            }
            // ---- P = exp2(S - m_run), row-sum (tree)
            #pragma unroll
            for (int r = 0; r < 16; ++r) {
                s0[r] = exp2f(s0[r] - m_run);
                s1[r] = exp2f(s1[r] - m_run);
            }
            float sm[8];
            #pragma unroll
            for (int r = 0; r < 8; ++r)
                sm[r] = (s0[r] + s0[r+8]) + (s1[r] + s1[r+8]);
            float rs = ((sm[0]+sm[1]) + (sm[2]+sm[3])) + ((sm[4]+sm[5]) + (sm[6]+sm[7]));
            rs += __shfl_xor(rs, 32);
            l_run += rs;

            // ---- pack P to bf16 words: x=(r2=0), y=(r2=1) halves per ks
            unsigned xw[4][2], yw[4][2];
            #pragma unroll
            for (int ks = 0; ks < 4; ++ks) {
                const f32x16& e = (ks & 2) ? s1 : s0;
                const int rb = (ks & 1) * 8;
                xw[ks][0] = cvtpk(e[rb + 0], e[rb + 1]);
                xw[ks][1] = cvtpk(e[rb + 2], e[rb + 3]);
                yw[ks][0] = cvtpk(e[rb + 4], e[rb + 5]);
                yw[ks][1] = cvtpk(e[rb + 6], e[rb + 7]);
            }
            // ---- PV: pb[ks] = P^T B-frag (k = kv = 16ks + 8hi + j) via pair exchange
            #pragma unroll
            for (int ks = 0; ks < 4; ++ks) {
                const unsigned sx0 = (unsigned)__shfl_xor((int)xw[ks][0], 32);
                const unsigned sx1 = (unsigned)__shfl_xor((int)xw[ks][1], 32);
                const unsigned sy0 = (unsigned)__shfl_xor((int)yw[ks][0], 32);
                const unsigned sy1 = (unsigned)__shfl_xor((int)yw[ks][1], 32);
                union { unsigned u[4]; bf16x8 v; } pb;
                pb.u[0] = hi ? sy0 : xw[ks][0];
                pb.u[1] = hi ? sy1 : xw[ks][1];
                pb.u[2] = hi ? yw[ks][0] : sx0;
                pb.u[3] = hi ? yw[ks][1] : sx1;
                const unsigned bc = ((unsigned)(32*ks + 16*hi)) ^ ((lq & 7) << 4);
                bf16x8 v0 = *(const bf16x8*)((const char*)&sV[buf][0] + lq*128 + bc);
                bf16x8 v1 = *(const bf16x8*)((const char*)&sV[buf][0] + (32 + lq)*128 + bc);
                accO0 = __builtin_amdgcn_mfma_f32_32x32x16_bf16(v0, pb.v, accO0, 0, 0, 0);
                accO1 = __builtin_amdgcn_mfma_f32_32x32x16_bf16(v1, pb.v, accO1, 0, 0, 0);
            }
        }
        asm volatile("s_waitcnt vmcnt(0)" ::: "memory");
        __syncthreads();
    }

    // ---- epilogue: normalize, write O[q][h*64 + d], d = 32dm + 8g + 4hi + (0..3)
    const float inv = 1.0f / l_run;
    u16* orow = O + (((size_t)(b * S_LEN) + q0w + lq)) * (NH*HD) + h*64;
    #pragma unroll
    for (int g = 0; g < 4; ++g) {
        uint2 w0, w1;
        w0.x = cvtpk(accO0[4*g + 0] * inv, accO0[4*g + 1] * inv);
        w0.y = cvtpk(accO0[4*g + 2] * inv, accO0[4*g + 3] * inv);
        *(uint2*)(orow + 8*g + 4*hi) = w0;
        w1.x = cvtpk(accO1[4*g + 0] * inv, accO1[4*g + 1] * inv);
        w1.y = cvtpk(accO1[4*g + 2] * inv, accO1[4*g + 3] * inv);
        *(uint2*)(orow + 32 + 8*g + 4*hi) = w1;
    }
}

// ---------------- host launcher ----------------
extern "C" void kernel_launch(void* const* d_in, const int* in_sizes, int n_in,
                              void* d_out, int out_size, void* d_ws, size_t ws_size,
                              hipStream_t stream) {
    const float* x  = (const float*)d_in[0];
    const float* Wq = (const float*)d_in[1];
    const float* bq = (const float*)d_in[2];
    const float* Wk = (const float*)d_in[3];
    const float* bk = (const float*)d_in[4];
    const float* Wv = (const float*)d_in[5];
    const float* bv = (const float*)d_in[6];
    const float* Wo = (const float*)d_in[7];
    const float* bo = (const float*)d_in[8];
    const float* kw = (const float*)d_in[9];

    uint8_t* ws = (uint8_t*)d_ws;
    // phase-1 layout
    u16*   xb    = (u16*)(ws);                    // [0, 16777216)
    u16*   wqkvb = (u16*)(ws + 16777216);         // [16777216, 29360128)
    u16*   wob   = (u16*)(ws + 29360128);         // [29360128, 37748736)
    float* qkvf  = (float*)(ws + 37748736);       // [37748736, 88080384)  (live through attn)
    float* bqkv  = (float*)(ws + 88080384);       // 12 KiB
    float* rtab  = (float*)(ws + 88092672);       // 512 KiB
    // phase-2 aliases
    u16*   ob    = (u16*)(ws);                    // over xb (dead after QKV gemm)
    u16*   kb    = (u16*)(ws + 16777216);         // over wqkvb (dead after QKV gemm)
    u16*   vtb   = (u16*)(ws + 20971520);         // over wqkvb tail

    // 1. convert all f32 tensors to bf16 (one launch)
    cvt_all<<<9216, 256, 0, stream>>>(x, Wq, Wk, Wv, Wo, xb, wqkvb, wob);
    build_bqkv<<<12, 256, 0, stream>>>(bq, bk, bv, bqkv);
    rope_table<<<256, 256, 0, stream>>>(rtab);

    // 2. QKV projection: [4096][3072] = xb @ wqkvb^T + bqkv
    gemm_bt<<<768, 256, 0, stream>>>(xb, wqkvb, bqkv, qkvf, NROWS, QKVN, HID);

    // 3. RoPE + pack K, transpose-pack V (Q-RoPE fused into attn)
    rope_pack_k<<<4096, 256, 0, stream>>>(qkvf, rtab, kb);
    pack_vt<<<dim3(32, 16), 256, 0, stream>>>(qkvf, vtb);

    // 4. causal flash attention: 512 blocks (8 q-tiles x 64 bh), 8 waves each
    attn_fwd<<<dim3(512), dim3(512), 0, stream>>>(qkvf, rtab, kw, kb, vtb, ob);

    // 5. output projection: d_out = ob @ Wo^T + bo
    gemm_bt<<<512, 256, 0, stream>>>(ob, wob, bo, (float*)d_out, NROWS, HID, HID);

    (void)in_sizes; (void)n_in; (void)out_size; (void)ws_size;
}

// Round 5
// 222.970 us; speedup vs baseline: 1.7789x; 1.0690x over previous
//
#include <hip/hip_runtime.h>
#include <stdint.h>

#define S_LEN 2048
#define HID   2048
#define NH    32
#define NKV   8
#define HD    64
#define BATCH 2
#define NROWS (BATCH * S_LEN)      // 4096
#define QKVN  (NH*HD + 2*NKV*HD)   // 3072

typedef unsigned short u16;
typedef __bf16 bf16_t;
typedef bf16_t bf16x8 __attribute__((ext_vector_type(8)));
typedef float  f32x4  __attribute__((ext_vector_type(4)));
typedef float  f32x16 __attribute__((ext_vector_type(16)));
typedef u16    u16x8  __attribute__((ext_vector_type(8)));

#define LOG2E 1.4426950408889634f

__device__ __forceinline__ u16 f2bf(float f) {
    union { float f; uint32_t u; } v; v.f = f;
    uint32_t u = v.u;
    return (u16)((u + 0x7fffu + ((u >> 16) & 1u)) >> 16);
}

__device__ __forceinline__ unsigned cvtpk(float a, float b) {
    unsigned r;
    asm("v_cvt_pk_bf16_f32 %0, %1, %2" : "=v"(r) : "v"(a), "v"(b));
    return r;
}

// v_permlane32_swap_b32 a, b:  a'[l>=32] = b[l-32];  b'[l<32] = a[l+32]; others keep.
__device__ __forceinline__ void plswap(unsigned &a, unsigned &b) {
    asm volatile("v_permlane32_swap_b32 %0, %1" : "+v"(a), "+v"(b));
}

__device__ __forceinline__ void llds16(const void* g, void* l) {
    __builtin_amdgcn_global_load_lds(
        (const __attribute__((address_space(1))) void*)g,
        (__attribute__((address_space(3))) void*)l,
        16, 0, 0);
}

// ---------------- fused f32 -> bf16 convert for all 5 tensors ----------------
__global__ void cvt_all(const float* __restrict__ x, const float* __restrict__ wq,
                        const float* __restrict__ wk, const float* __restrict__ wv,
                        const float* __restrict__ wo,
                        u16* __restrict__ xb, u16* __restrict__ wqkvb, u16* __restrict__ wob) {
    int e = blockIdx.x * 256 + threadIdx.x;   // 8-elem group index
    const float* s; u16* d; int o;
    if (e < 1048576)      { s = x;  d = xb;                 o = e; }
    else if (e < 1572864) { s = wq; d = wqkvb;              o = e - 1048576; }
    else if (e < 1703936) { s = wk; d = wqkvb + 2048*2048;  o = e - 1572864; }
    else if (e < 1835008) { s = wv; d = wqkvb + 2560*2048;  o = e - 1703936; }
    else                  { s = wo; d = wob;                o = e - 1835008; }
    const float4* sp = (const float4*)s;
    float4 a = sp[2*(size_t)o], b = sp[2*(size_t)o + 1];
    u16x8 r;
    r[0]=f2bf(a.x); r[1]=f2bf(a.y); r[2]=f2bf(a.z); r[3]=f2bf(a.w);
    r[4]=f2bf(b.x); r[5]=f2bf(b.y); r[6]=f2bf(b.z); r[7]=f2bf(b.w);
    *(u16x8*)(d + 8*(size_t)o) = r;
}

// ---------------- concat bias (bq|bk|bv) ----------------
__global__ void build_bqkv(const float* __restrict__ bq, const float* __restrict__ bk,
                           const float* __restrict__ bv, float* __restrict__ bqkv) {
    int i = blockIdx.x * 256 + threadIdx.x;
    if (i >= QKVN) return;
    bqkv[i] = (i < 2048) ? bq[i] : (i < 2560 ? bk[i - 2048] : bv[i - 2560]);
}

// ---------------- RoPE table: cos at [0:65536), sin at [65536:131072) ----------------
__global__ void rope_table(float* __restrict__ tab) {
    int idx = blockIdx.x * 256 + threadIdx.x;   // s*32 + i
    if (idx >= S_LEN * 32) return;
    int i = idx & 31, s = idx >> 5;
    float invf = exp2f(-(float)i * (13.287712379549449f / 32.0f));
    float ang = (float)s * invf;
    float sn, cs;
    sincosf(ang, &sn, &cs);
    tab[idx] = cs;
    tab[S_LEN*32 + idx] = sn;
}

// ---------------- QKV GEMM with fused RoPE/pack epilogue ----------------
// C = xb[4096][2048] @ wqkvb[3072][2048]^T + bqkv, then per column range:
//   cols [0,2048):    Q -> RoPE, * SCALE*kw[h]*log2e, bf16 qpk[b*32+h][s][64]
//   cols [2048,2560): K -> RoPE,                      bf16 kpk[b*8+kvh][s][64]
//   cols [2560,3072): V ->                            bf16 vlin[row][512]
__global__ __launch_bounds__(256) void gemm_qkv(
    const u16* __restrict__ A, const u16* __restrict__ Bw,
    const float* __restrict__ bias, const float* __restrict__ rtab,
    const float* __restrict__ kw,
    u16* __restrict__ qpk, u16* __restrict__ kpk, u16* __restrict__ vlin)
{
    const int M = NROWS, N = QKVN, K = HID;
    const int nbm = M >> 7, nbn = N >> 7;
    const int nwg = nbm * nbn;          // 768
    int wg = blockIdx.x;
    wg = (wg & 7) * (nwg >> 3) + (wg >> 3);   // XCD swizzle
    const int bm = wg % nbm, bn = wg / nbm;
    const int brow = bm << 7, bcol = bn << 7;

    __shared__ u16 sA[128 * 32];
    __shared__ u16 sB[128 * 32];

    const int t = threadIdx.x;
    const int lane = t & 63, wid = t >> 6;
    const int wr = wid >> 1, wc = wid & 1;
    const int lr = lane & 15, lhi = lane >> 4;

    f32x4 acc[4][4] = {};

    for (int k0 = 0; k0 < K; k0 += 32) {
        __syncthreads();
        #pragma unroll
        for (int i = 0; i < 2; ++i) {
            const unsigned off = ((unsigned)t << 4) + ((unsigned)i << 12); // bytes
            const unsigned row = off >> 6;          // 64 B per row (32 bf16)
            const unsigned ce  = (off & 63) >> 1;   // elem col
            llds16(A  + (size_t)(brow + row) * K + (k0 + ce), sA + (off >> 1));
            llds16(Bw + (size_t)(bcol + row) * K + (k0 + ce), sB + (off >> 1));
        }
        __syncthreads();
        bf16x8 af[4], bfv[4];
        #pragma unroll
        for (int m = 0; m < 4; ++m)
            af[m] = *(const bf16x8*)(sA + ((wr*64 + m*16 + lr) * 32 + lhi*8));
        #pragma unroll
        for (int n = 0; n < 4; ++n)
            bfv[n] = *(const bf16x8*)(sB + ((wc*64 + n*16 + lr) * 32 + lhi*8));
        #pragma unroll
        for (int m = 0; m < 4; ++m)
            #pragma unroll
            for (int n = 0; n < 4; ++n)
                acc[m][n] = __builtin_amdgcn_mfma_f32_16x16x32_bf16(af[m], bfv[n], acc[m][n], 0, 0, 0);
    }

    const int c64 = bcol + wc*64;        // 64-aligned col span base
    const int hb  = c64 >> 6;            // 0..47: <32 Q head, <40 K head, else V
    const int rowb = brow + wr*64;

    if (hb < 40) {
        const bool isQ = hb < 32;
        const float sc = isQ ? (0.125f * LOG2E * kw[hb]) : 1.0f;
        u16* dst = isQ ? qpk : kpk;
        const int nheads = isQ ? 32 : 8;
        const int hloc = isQ ? hb : (hb - 32);
        #pragma unroll
        for (int m = 0; m < 4; ++m) {
            #pragma unroll
            for (int n = 0; n < 2; ++n) {
                const int i = n*16 + lr;
                const float b1 = bias[c64 + i];
                const float b2 = bias[c64 + i + 32];
                #pragma unroll
                for (int j = 0; j < 4; ++j) {
                    const int row = rowb + m*16 + lhi*4 + j;
                    const int s = row & (S_LEN - 1);
                    const int bb = row >> 11;
                    const float x1 = acc[m][n][j] + b1;
                    const float x2 = acc[m][n+2][j] + b2;
                    const float cs = rtab[s*32 + i];
                    const float sn = rtab[S_LEN*32 + s*32 + i];
                    const size_t base = ((size_t)(bb*nheads + hloc)) * (S_LEN*64) + (size_t)s*64;
                    dst[base + i]      = f2bf((x1*cs - x2*sn) * sc);
                    dst[base + i + 32] = f2bf((x2*cs + x1*sn) * sc);
                }
            }
        }
    } else {
        #pragma unroll
        for (int m = 0; m < 4; ++m) {
            #pragma unroll
            for (int n = 0; n < 4; ++n) {
                const int col = c64 + n*16 + lr;
                const float bv = bias[col];
                #pragma unroll
                for (int j = 0; j < 4; ++j) {
                    const int row = rowb + m*16 + lhi*4 + j;
                    vlin[(size_t)row * 512 + (col - 2560)] = f2bf(acc[m][n][j] + bv);
                }
            }
        }
    }
}

// ---------------- bf16 GEMM, C[M][N] = A[M][K] * Bw[N][K]^T + bias[n] (o-proj) ----------------
__global__ __launch_bounds__(256) void gemm_bt(
    const u16* __restrict__ A, const u16* __restrict__ Bw,
    const float* __restrict__ bias, float* __restrict__ C,
    int M, int N, int K)
{
    const int nbm = M >> 7, nbn = N >> 7;
    const int nwg = nbm * nbn;
    int wg = blockIdx.x;
    wg = (wg & 7) * (nwg >> 3) + (wg >> 3);   // XCD swizzle (nwg % 8 == 0)
    const int bm = wg % nbm, bn = wg / nbm;
    const int brow = bm << 7, bcol = bn << 7;

    __shared__ u16 sA[128 * 32];
    __shared__ u16 sB[128 * 32];

    const int t = threadIdx.x;
    const int lane = t & 63, wid = t >> 6;
    const int wr = wid >> 1, wc = wid & 1;
    const int lr = lane & 15, lhi = lane >> 4;

    f32x4 acc[4][4] = {};

    for (int k0 = 0; k0 < K; k0 += 32) {
        __syncthreads();
        #pragma unroll
        for (int i = 0; i < 2; ++i) {
            const unsigned off = ((unsigned)t << 4) + ((unsigned)i << 12); // bytes
            const unsigned row = off >> 6;
            const unsigned ce  = (off & 63) >> 1;
            llds16(A  + (size_t)(brow + row) * K + (k0 + ce), sA + (off >> 1));
            llds16(Bw + (size_t)(bcol + row) * K + (k0 + ce), sB + (off >> 1));
        }
        __syncthreads();
        bf16x8 af[4], bfv[4];
        #pragma unroll
        for (int m = 0; m < 4; ++m)
            af[m] = *(const bf16x8*)(sA + ((wr*64 + m*16 + lr) * 32 + lhi*8));
        #pragma unroll
        for (int n = 0; n < 4; ++n)
            bfv[n] = *(const bf16x8*)(sB + ((wc*64 + n*16 + lr) * 32 + lhi*8));
        #pragma unroll
        for (int m = 0; m < 4; ++m)
            #pragma unroll
            for (int n = 0; n < 4; ++n)
                acc[m][n] = __builtin_amdgcn_mfma_f32_16x16x32_bf16(af[m], bfv[n], acc[m][n], 0, 0, 0);
    }

    #pragma unroll
    for (int m = 0; m < 4; ++m) {
        #pragma unroll
        for (int n = 0; n < 4; ++n) {
            const int col = bcol + wc*64 + n*16 + lr;
            const float bv = bias[col];
            #pragma unroll
            for (int j = 0; j < 4; ++j) {
                const int row = brow + wr*64 + m*16 + lhi*4 + j;
                C[(size_t)row * N + col] = acc[m][n][j] + bv;
            }
        }
    }
}

// ---------------- pack V transposed: bf16 vlin[row][512] -> vtb[b*8+kvh][64][S] ----------------
__global__ void pack_vt(const u16* __restrict__ vlin, u16* __restrict__ vtb) {
    __shared__ u16 tile[64][67];
    const int st = blockIdx.x;          // s-tile
    const int bk = blockIdx.y;          // b*8 + kvh
    const int t = threadIdx.x;
    const int b = bk >> 3, kvh = bk & 7;
    const int r = t >> 2, cg = (t & 3) << 4;
    const u16* src = vlin + ((size_t)(b*S_LEN + st*64 + r)) * 512 + kvh*64 + cg;
    #pragma unroll
    for (int j = 0; j < 16; ++j) tile[r][cg + j] = src[j];
    __syncthreads();
    const int d = t >> 2, sg = (t & 3) << 4;
    u16* dst = vtb + ((size_t)(bk*64 + d)) * S_LEN + st*64 + sg;
    #pragma unroll
    for (int j = 0; j < 16; ++j) dst[j] = tile[sg + j][d];
}

// ---------------- flash attention: 8 waves x 32 q-rows, swapped 32x32 MFMA ----------------
// Q pre-packed/scaled bf16. QK^T as mfma(K,Q) -> P lane-local (col=lane&31=q);
// PV as mfma(Vt,P^T). acc-init = -m_run (no subs in common path); permlane32 P-exchange.
__global__ __launch_bounds__(512, 4) void attn_fwd(
    const u16* __restrict__ Q,      // [B*NH][S][64] packed, scaled
    const u16* __restrict__ Kk,     // [B*NKV][S][64]
    const u16* __restrict__ Vt,     // [B*NKV][64][S]
    u16* __restrict__ O)            // [B*S][NH*64]
{
    __shared__ u16 sK[2][64 * 64];
    __shared__ u16 sV[2][64 * 64];

    const int t = threadIdx.x;
    const int lane = t & 63, wid = t >> 6;
    const int hi = lane >> 5, lq = lane & 31;
    const int bid = blockIdx.x;
    // balanced pairing: bid & bid+256 qb's sum to 7
    const int qb = (bid < 256) ? (7 - (bid >> 6)) : ((bid >> 6) - 4);
    const int bh = bid & 63;
    const int b = bh >> 5, h = bh & 31;
    const int kvh = h >> 2;

    const u16* Kp = Kk + ((size_t)(b*NKV + kvh)) * (S_LEN * 64);
    const u16* Vp = Vt + ((size_t)(b*NKV + kvh)) * (64 * S_LEN);

    const int q0w = qb*256 + wid*32;        // wave's first q row
    const int qg  = q0w + lq;               // this lane's q row

    // Q B-operand frags: col=q=lq, k(d) = 16*kd + 8*hi + j
    const u16* Qrow = Q + (((size_t)bh) * S_LEN + qg) * 64 + 8*hi;
    bf16x8 qf[4];
    #pragma unroll
    for (int kd = 0; kd < 4; ++kd)
        qf[kd] = *(const bf16x8*)(Qrow + 16*kd);

    f32x16 accO0 = {}, accO1 = {};          // O[q=lq][d = crow(r,hi) + 32*dm]
    float m_run = 0.f, l_run = 0.f;         // scores bounded; 0-start safe w/ defer-max

    const int ntB = 4*qb + 4;
    const int tmax_w = (q0w + 31) >> 6;     // last tile this wave needs

    // prologue: stage tile 0 into buf 0 (pre-swizzled source, linear LDS dest)
    {
        const unsigned row = t >> 3, cb = (t & 7) << 4;
        const unsigned scb = cb ^ ((row & 7) << 4);
        llds16(Kp + (size_t)row * 64 + (scb >> 1), &sK[0][0] + t*8);
        llds16(Vp + (size_t)row * S_LEN + (scb >> 1), &sV[0][0] + t*8);
    }
    asm volatile("s_waitcnt vmcnt(0)" ::: "memory");
    __syncthreads();

    for (int tt = 0; tt < ntB; ++tt) {
        const int buf = tt & 1;
        const int kv0 = tt * 64;
        if (tt + 1 < ntB) {                 // stage next tile into other buffer
            const int kvn = kv0 + 64;
            const unsigned row = t >> 3, cb = (t & 7) << 4;
            const unsigned scb = cb ^ ((row & 7) << 4);
            llds16(Kp + (size_t)(kvn + row) * 64 + (scb >> 1), &sK[buf^1][0] + t*8);
            llds16(Vp + (size_t)row * S_LEN + kvn + (scb >> 1), &sV[buf^1][0] + t*8);
        }
        if (tt <= tmax_w) {
            // ---- QK^T (swapped), acc pre-biased with -m_run: s' = QK - m_run
            const float nm = -m_run;
            f32x16 s0, s1;
            #pragma unroll
            for (int r = 0; r < 16; ++r) { s0[r] = nm; s1[r] = nm; }
            #pragma unroll
            for (int kd = 0; kd < 4; ++kd) {
                const unsigned bc = ((unsigned)(32*kd + 16*hi)) ^ ((lq & 7) << 4);
                bf16x8 k0 = *(const bf16x8*)((const char*)&sK[buf][0] + lq*128 + bc);
                bf16x8 k1 = *(const bf16x8*)((const char*)&sK[buf][0] + (32 + lq)*128 + bc);
                s0 = __builtin_amdgcn_mfma_f32_32x32x16_bf16(k0, qf[kd], s0, 0, 0, 0);
                s1 = __builtin_amdgcn_mfma_f32_32x32x16_bf16(k1, qf[kd], s1, 0, 0, 0);
            }
            // ---- causal mask (diagonal-overlapping tiles only)
            if (kv0 + 63 > q0w) {
                #pragma unroll
                for (int r = 0; r < 16; ++r) {
                    const int kvg = kv0 + (r & 3) + 8*(r >> 2) + 4*hi;
                    if (kvg > qg)      s0[r] = -INFINITY;
                    if (kvg + 32 > qg) s1[r] = -INFINITY;
                }
            }
            // ---- tile max (tree) + half-wave combine; tm is relative to m_run
            float mx[8];
            #pragma unroll
            for (int r = 0; r < 8; ++r)
                mx[r] = fmaxf(fmaxf(s0[r], s0[r+8]), fmaxf(s1[r], s1[r+8]));
            float tm = fmaxf(fmaxf(fmaxf(mx[0], mx[1]), fmaxf(mx[2], mx[3])),
                             fmaxf(fmaxf(mx[4], mx[5]), fmaxf(mx[6], mx[7])));
            tm = fmaxf(tm, __shfl_xor(tm, 32));
            // ---- defer-max: rescale only when tile max outgrew m_run by >8
            if (!__all(tm <= 8.0f)) {
                const float dd = fmaxf(tm, 0.f);
                const float al = __builtin_amdgcn_exp2f(-dd);
                m_run += dd;
                l_run *= al;
                #pragma unroll
                for (int r = 0; r < 16; ++r) { accO0[r] *= al; accO1[r] *= al; }
                #pragma unroll
                for (int r = 0; r < 16; ++r) { s0[r] -= dd; s1[r] -= dd; }
            }
            // ---- P = exp2(s'), row-sum (tree)
            #pragma unroll
            for (int r = 0; r < 16; ++r) {
                s0[r] = __builtin_amdgcn_exp2f(s0[r]);
                s1[r] = __builtin_amdgcn_exp2f(s1[r]);
            }
            float sm[8];
            #pragma unroll
            for (int r = 0; r < 8; ++r)
                sm[r] = (s0[r] + s0[r+8]) + (s1[r] + s1[r+8]);
            float rs = ((sm[0]+sm[1]) + (sm[2]+sm[3])) + ((sm[4]+sm[5]) + (sm[6]+sm[7]));
            rs += __shfl_xor(rs, 32);
            l_run += rs;

            // ---- P->bf16 + half-wave exchange via permlane32_swap; PV MFMA
            #pragma unroll
            for (int ks = 0; ks < 4; ++ks) {
                const f32x16& e = (ks & 2) ? s1 : s0;
                const int rb = (ks & 1) * 8;
                unsigned x0 = cvtpk(e[rb + 0], e[rb + 1]);
                unsigned x1 = cvtpk(e[rb + 2], e[rb + 3]);
                unsigned y0 = cvtpk(e[rb + 4], e[rb + 5]);
                unsigned y1 = cvtpk(e[rb + 6], e[rb + 7]);
                plswap(x0, y0);   // -> pb.u[0], pb.u[2]
                plswap(x1, y1);   // -> pb.u[1], pb.u[3]
                union { unsigned u[4]; bf16x8 v; } pb;
                pb.u[0] = x0; pb.u[1] = x1; pb.u[2] = y0; pb.u[3] = y1;
                const unsigned bc = ((unsigned)(32*ks + 16*hi)) ^ ((lq & 7) << 4);
                bf16x8 v0 = *(const bf16x8*)((const char*)&sV[buf][0] + lq*128 + bc);
                bf16x8 v1 = *(const bf16x8*)((const char*)&sV[buf][0] + (32 + lq)*128 + bc);
                accO0 = __builtin_amdgcn_mfma_f32_32x32x16_bf16(v0, pb.v, accO0, 0, 0, 0);
                accO1 = __builtin_amdgcn_mfma_f32_32x32x16_bf16(v1, pb.v, accO1, 0, 0, 0);
            }
        }
        asm volatile("s_waitcnt vmcnt(0)" ::: "memory");
        __syncthreads();
    }

    // ---- epilogue: normalize, write O[q][h*64 + d], d = 32dm + 8g + 4hi + (0..3)
    const float inv = 1.0f / l_run;
    u16* orow = O + (((size_t)(b * S_LEN) + q0w + lq)) * (NH*HD) + h*64;
    #pragma unroll
    for (int g = 0; g < 4; ++g) {
        uint2 w0, w1;
        w0.x = cvtpk(accO0[4*g + 0] * inv, accO0[4*g + 1] * inv);
        w0.y = cvtpk(accO0[4*g + 2] * inv, accO0[4*g + 3] * inv);
        *(uint2*)(orow + 8*g + 4*hi) = w0;
        w1.x = cvtpk(accO1[4*g + 0] * inv, accO1[4*g + 1] * inv);
        w1.y = cvtpk(accO1[4*g + 2] * inv, accO1[4*g + 3] * inv);
        *(uint2*)(orow + 32 + 8*g + 4*hi) = w1;
    }
}

// ---------------- host launcher ----------------
extern "C" void kernel_launch(void* const* d_in, const int* in_sizes, int n_in,
                              void* d_out, int out_size, void* d_ws, size_t ws_size,
                              hipStream_t stream) {
    const float* x  = (const float*)d_in[0];
    const float* Wq = (const float*)d_in[1];
    const float* bq = (const float*)d_in[2];
    const float* Wk = (const float*)d_in[3];
    const float* bk = (const float*)d_in[4];
    const float* Wv = (const float*)d_in[5];
    const float* bv = (const float*)d_in[6];
    const float* Wo = (const float*)d_in[7];
    const float* bo = (const float*)d_in[8];
    const float* kw = (const float*)d_in[9];

    uint8_t* ws = (uint8_t*)d_ws;
    u16*   xb    = (u16*)(ws);                    // 16 MiB
    u16*   wqkvb = (u16*)(ws + 16777216);         // 12 MiB
    u16*   wob   = (u16*)(ws + 29360128);         //  8 MiB
    u16*   qpk   = (u16*)(ws + 37748736);         // 16 MiB  [B*NH][S][64]
    u16*   kpk   = (u16*)(ws + 54525952);         //  4 MiB  [B*NKV][S][64]
    u16*   vlin  = (u16*)(ws + 58720256);         //  4 MiB  [4096][512]
    u16*   vtb   = (u16*)(ws + 62914560);         //  4 MiB  [B*NKV][64][S]
    u16*   ob    = (u16*)(ws + 67108864);         // 16 MiB  [B*S][2048]
    float* bqkv  = (float*)(ws + 83886080);       // 12 KiB
    float* rtab  = (float*)(ws + 83898368);       // 512 KiB

    // 1. convert inputs to bf16; bias concat; RoPE table
    cvt_all<<<9216, 256, 0, stream>>>(x, Wq, Wk, Wv, Wo, xb, wqkvb, wob);
    build_bqkv<<<12, 256, 0, stream>>>(bq, bk, bv, bqkv);
    rope_table<<<256, 256, 0, stream>>>(rtab);

    // 2. QKV projection + fused RoPE/scale/pack epilogue
    gemm_qkv<<<768, 256, 0, stream>>>(xb, wqkvb, bqkv, rtab, kw, qpk, kpk, vlin);

    // 3. transpose-pack V (bf16 -> bf16)
    pack_vt<<<dim3(32, 16), 256, 0, stream>>>(vlin, vtb);

    // 4. causal flash attention: 512 blocks (8 q-tiles x 64 bh), 8 waves each
    attn_fwd<<<dim3(512), dim3(512), 0, stream>>>(qpk, kpk, vtb, ob);

    // 5. output projection: d_out = ob @ Wo^T + bo
    gemm_bt<<<512, 256, 0, stream>>>(ob, wob, bo, (float*)d_out, NROWS, HID, HID);

    (void)in_sizes; (void)n_in; (void)out_size; (void)ws_size;
}

// Round 6
// 194.104 us; speedup vs baseline: 2.0435x; 1.1487x over previous
//
#include <hip/hip_runtime.h>
#include <stdint.h>

#define S_LEN 2048
#define HID   2048
#define NH    32
#define NKV   8
#define HD    64
#define BATCH 2
#define NROWS (BATCH * S_LEN)      // 4096
#define QKVN  (NH*HD + 2*NKV*HD)   // 3072

typedef unsigned short u16;
typedef __bf16 bf16_t;
typedef bf16_t bf16x8 __attribute__((ext_vector_type(8)));
typedef float  f32x4  __attribute__((ext_vector_type(4)));
typedef float  f32x16 __attribute__((ext_vector_type(16)));
typedef u16    u16x8  __attribute__((ext_vector_type(8)));

#define LOG2E 1.4426950408889634f

__device__ __forceinline__ u16 f2bf(float f) {
    union { float f; uint32_t u; } v; v.f = f;
    uint32_t u = v.u;
    return (u16)((u + 0x7fffu + ((u >> 16) & 1u)) >> 16);
}

__device__ __forceinline__ unsigned cvtpk(float a, float b) {
    unsigned r;
    asm("v_cvt_pk_bf16_f32 %0, %1, %2" : "=v"(r) : "v"(a), "v"(b));
    return r;
}

// v_permlane32_swap_b32 a, b:  a'[l>=32] = b[l-32];  b'[l<32] = a[l+32]  (HW-verified R5)
__device__ __forceinline__ void plswap(unsigned &a, unsigned &b) {
    asm volatile("v_permlane32_swap_b32 %0, %1" : "+v"(a), "+v"(b));
}

__device__ __forceinline__ void llds16(const void* g, void* l) {
    __builtin_amdgcn_global_load_lds(
        (const __attribute__((address_space(1))) void*)g,
        (__attribute__((address_space(3))) void*)l,
        16, 0, 0);
}

// counted-vmcnt barrier: wait for all but N newest VMEM ops, then raw barrier.
#define CBAR(N) do { \
    asm volatile("s_waitcnt vmcnt(" #N ")" ::: "memory"); \
    __builtin_amdgcn_s_barrier(); \
    __builtin_amdgcn_sched_barrier(0); \
} while (0)

// ---------------- fused f32 -> bf16 convert for all 5 tensors ----------------
__global__ void cvt_all(const float* __restrict__ x, const float* __restrict__ wq,
                        const float* __restrict__ wk, const float* __restrict__ wv,
                        const float* __restrict__ wo,
                        u16* __restrict__ xb, u16* __restrict__ wqkvb, u16* __restrict__ wob) {
    int e = blockIdx.x * 256 + threadIdx.x;   // 8-elem group index
    const float* s; u16* d; int o;
    if (e < 1048576)      { s = x;  d = xb;                 o = e; }
    else if (e < 1572864) { s = wq; d = wqkvb;              o = e - 1048576; }
    else if (e < 1703936) { s = wk; d = wqkvb + 2048*2048;  o = e - 1572864; }
    else if (e < 1835008) { s = wv; d = wqkvb + 2560*2048;  o = e - 1703936; }
    else                  { s = wo; d = wob;                o = e - 1835008; }
    const float4* sp = (const float4*)s;
    float4 a = sp[2*(size_t)o], b = sp[2*(size_t)o + 1];
    u16x8 r;
    r[0]=f2bf(a.x); r[1]=f2bf(a.y); r[2]=f2bf(a.z); r[3]=f2bf(a.w);
    r[4]=f2bf(b.x); r[5]=f2bf(b.y); r[6]=f2bf(b.z); r[7]=f2bf(b.w);
    *(u16x8*)(d + 8*(size_t)o) = r;
}

// ---------------- concat bias (bq|bk|bv) ----------------
__global__ void build_bqkv(const float* __restrict__ bq, const float* __restrict__ bk,
                           const float* __restrict__ bv, float* __restrict__ bqkv) {
    int i = blockIdx.x * 256 + threadIdx.x;
    if (i >= QKVN) return;
    bqkv[i] = (i < 2048) ? bq[i] : (i < 2560 ? bk[i - 2048] : bv[i - 2560]);
}

// ---------------- RoPE table: cos at [0:65536), sin at [65536:131072) ----------------
__global__ void rope_table(float* __restrict__ tab) {
    int idx = blockIdx.x * 256 + threadIdx.x;   // s*32 + i
    if (idx >= S_LEN * 32) return;
    int i = idx & 31, s = idx >> 5;
    float invf = exp2f(-(float)i * (13.287712379549449f / 32.0f));
    float ang = (float)s * invf;
    float sn, cs;
    sincosf(ang, &sn, &cs);
    tab[idx] = cs;
    tab[S_LEN*32 + idx] = sn;
}

// ---------------- QKV GEMM (depth-2 counted pipeline) + fused RoPE/pack epilogue ----------------
__global__ __launch_bounds__(256) void gemm_qkv(
    const u16* __restrict__ A, const u16* __restrict__ Bw,
    const float* __restrict__ bias, const float* __restrict__ rtab,
    const float* __restrict__ kw,
    u16* __restrict__ qpk, u16* __restrict__ kpk, u16* __restrict__ vlin)
{
    const int M = NROWS, N = QKVN, K = HID;
    const int nbm = M >> 7, nbn = N >> 7;
    const int nwg = nbm * nbn;          // 768
    int wg = blockIdx.x;
    wg = (wg & 7) * (nwg >> 3) + (wg >> 3);   // XCD swizzle
    const int bm = wg % nbm, bn = wg / nbm;
    const int brow = bm << 7, bcol = bn << 7;

    __shared__ u16 sbuf[3][8192];   // per buf: A tile u16[0,4096), B tile [4096,8192)

    const int t = threadIdx.x;
    const int lane = t & 63, wid = t >> 6;
    const int wr = wid >> 1, wc = wid & 1;
    const int lr = lane & 15, lhi = lane >> 4;

    auto stage = [&](int kt, int bi) {
        const int k0 = kt << 5;
        #pragma unroll
        for (int i = 0; i < 2; ++i) {
            const unsigned off = ((unsigned)t << 4) + ((unsigned)i << 12); // bytes
            const unsigned row = off >> 6;          // 64 B per row (32 bf16)
            const unsigned ce  = (off & 63) >> 1;   // elem col
            llds16(A  + (size_t)(brow + row) * K + (k0 + ce), &sbuf[bi][0]    + (off >> 1));
            llds16(Bw + (size_t)(bcol + row) * K + (k0 + ce), &sbuf[bi][4096] + (off >> 1));
        }
    };

    f32x4 acc[4][4] = {};
    const int nk = K >> 5;   // 64

    stage(0, 0);
    stage(1, 1);
    int cur = 0, st2 = 2;
    for (int kt = 0; kt < nk; ++kt) {
        if (kt < nk - 1) CBAR(4); else CBAR(0);
        if (kt + 2 < nk) stage(kt + 2, st2);
        const u16* sA = &sbuf[cur][0];
        const u16* sB = &sbuf[cur][4096];
        bf16x8 af[4], bfv[4];
        #pragma unroll
        for (int m = 0; m < 4; ++m)
            af[m] = *(const bf16x8*)(sA + ((wr*64 + m*16 + lr) * 32 + lhi*8));
        #pragma unroll
        for (int n = 0; n < 4; ++n)
            bfv[n] = *(const bf16x8*)(sB + ((wc*64 + n*16 + lr) * 32 + lhi*8));
        #pragma unroll
        for (int m = 0; m < 4; ++m)
            #pragma unroll
            for (int n = 0; n < 4; ++n)
                acc[m][n] = __builtin_amdgcn_mfma_f32_16x16x32_bf16(af[m], bfv[n], acc[m][n], 0, 0, 0);
        cur = (cur == 2) ? 0 : cur + 1;
        st2 = (st2 == 2) ? 0 : st2 + 1;
    }

    const int c64 = bcol + wc*64;        // 64-aligned col span base
    const int hb  = c64 >> 6;            // 0..47: <32 Q head, <40 K head, else V
    const int rowb = brow + wr*64;

    if (hb < 40) {
        const bool isQ = hb < 32;
        const float sc = isQ ? (0.125f * LOG2E * kw[hb]) : 1.0f;
        u16* dst = isQ ? qpk : kpk;
        const int nheads = isQ ? 32 : 8;
        const int hloc = isQ ? hb : (hb - 32);
        #pragma unroll
        for (int m = 0; m < 4; ++m) {
            #pragma unroll
            for (int n = 0; n < 2; ++n) {
                const int i = n*16 + lr;
                const float b1 = bias[c64 + i];
                const float b2 = bias[c64 + i + 32];
                #pragma unroll
                for (int j = 0; j < 4; ++j) {
                    const int row = rowb + m*16 + lhi*4 + j;
                    const int s = row & (S_LEN - 1);
                    const int bb = row >> 11;
                    const float x1 = acc[m][n][j] + b1;
                    const float x2 = acc[m][n+2][j] + b2;
                    const float cs = rtab[s*32 + i];
                    const float sn = rtab[S_LEN*32 + s*32 + i];
                    const size_t base = ((size_t)(bb*nheads + hloc)) * (S_LEN*64) + (size_t)s*64;
                    dst[base + i]      = f2bf((x1*cs - x2*sn) * sc);
                    dst[base + i + 32] = f2bf((x2*cs + x1*sn) * sc);
                }
            }
        }
    } else {
        #pragma unroll
        for (int m = 0; m < 4; ++m) {
            #pragma unroll
            for (int n = 0; n < 4; ++n) {
                const int col = c64 + n*16 + lr;
                const float bv = bias[col];
                #pragma unroll
                for (int j = 0; j < 4; ++j) {
                    const int row = rowb + m*16 + lhi*4 + j;
                    vlin[(size_t)row * 512 + (col - 2560)] = f2bf(acc[m][n][j] + bv);
                }
            }
        }
    }
}

// ---------------- o-proj GEMM (depth-2 counted pipeline), C = A @ Bw^T + bias ----------------
__global__ __launch_bounds__(256) void gemm_bt(
    const u16* __restrict__ A, const u16* __restrict__ Bw,
    const float* __restrict__ bias, float* __restrict__ C,
    int M, int N, int K)
{
    const int nbm = M >> 7, nbn = N >> 7;
    const int nwg = nbm * nbn;
    int wg = blockIdx.x;
    wg = (wg & 7) * (nwg >> 3) + (wg >> 3);   // XCD swizzle (nwg % 8 == 0)
    const int bm = wg % nbm, bn = wg / nbm;
    const int brow = bm << 7, bcol = bn << 7;

    __shared__ u16 sbuf[3][8192];

    const int t = threadIdx.x;
    const int lane = t & 63, wid = t >> 6;
    const int wr = wid >> 1, wc = wid & 1;
    const int lr = lane & 15, lhi = lane >> 4;

    auto stage = [&](int kt, int bi) {
        const int k0 = kt << 5;
        #pragma unroll
        for (int i = 0; i < 2; ++i) {
            const unsigned off = ((unsigned)t << 4) + ((unsigned)i << 12);
            const unsigned row = off >> 6;
            const unsigned ce  = (off & 63) >> 1;
            llds16(A  + (size_t)(brow + row) * K + (k0 + ce), &sbuf[bi][0]    + (off >> 1));
            llds16(Bw + (size_t)(bcol + row) * K + (k0 + ce), &sbuf[bi][4096] + (off >> 1));
        }
    };

    f32x4 acc[4][4] = {};
    const int nk = K >> 5;

    stage(0, 0);
    stage(1, 1);
    int cur = 0, st2 = 2;
    for (int kt = 0; kt < nk; ++kt) {
        if (kt < nk - 1) CBAR(4); else CBAR(0);
        if (kt + 2 < nk) stage(kt + 2, st2);
        const u16* sA = &sbuf[cur][0];
        const u16* sB = &sbuf[cur][4096];
        bf16x8 af[4], bfv[4];
        #pragma unroll
        for (int m = 0; m < 4; ++m)
            af[m] = *(const bf16x8*)(sA + ((wr*64 + m*16 + lr) * 32 + lhi*8));
        #pragma unroll
        for (int n = 0; n < 4; ++n)
            bfv[n] = *(const bf16x8*)(sB + ((wc*64 + n*16 + lr) * 32 + lhi*8));
        #pragma unroll
        for (int m = 0; m < 4; ++m)
            #pragma unroll
            for (int n = 0; n < 4; ++n)
                acc[m][n] = __builtin_amdgcn_mfma_f32_16x16x32_bf16(af[m], bfv[n], acc[m][n], 0, 0, 0);
        cur = (cur == 2) ? 0 : cur + 1;
        st2 = (st2 == 2) ? 0 : st2 + 1;
    }

    #pragma unroll
    for (int m = 0; m < 4; ++m) {
        #pragma unroll
        for (int n = 0; n < 4; ++n) {
            const int col = bcol + wc*64 + n*16 + lr;
            const float bv = bias[col];
            #pragma unroll
            for (int j = 0; j < 4; ++j) {
                const int row = brow + wr*64 + m*16 + lhi*4 + j;
                C[(size_t)row * N + col] = acc[m][n][j] + bv;
            }
        }
    }
}

// ---------------- pack V transposed: bf16 vlin[row][512] -> vtb[b*8+kvh][64][S] ----------------
__global__ void pack_vt(const u16* __restrict__ vlin, u16* __restrict__ vtb) {
    __shared__ u16 tile[64][67];
    const int st = blockIdx.x;          // s-tile
    const int bk = blockIdx.y;          // b*8 + kvh
    const int t = threadIdx.x;
    const int b = bk >> 3, kvh = bk & 7;
    const int r = t >> 2, cg = (t & 3) << 4;
    const u16* src = vlin + ((size_t)(b*S_LEN + st*64 + r)) * 512 + kvh*64 + cg;
    #pragma unroll
    for (int j = 0; j < 16; ++j) tile[r][cg + j] = src[j];
    __syncthreads();
    const int d = t >> 2, sg = (t & 3) << 4;
    u16* dst = vtb + ((size_t)(bk*64 + d)) * S_LEN + st*64 + sg;
    #pragma unroll
    for (int j = 0; j < 16; ++j) dst[j] = tile[sg + j][d];
}

// ---------------- flash attention: 8 waves x 32 q-rows, swapped 32x32 MFMA ----------------
// depth-2 counted KV pipeline (triple-buffered). Q pre-packed/scaled bf16.
__global__ __launch_bounds__(512, 4) void attn_fwd(
    const u16* __restrict__ Q,      // [B*NH][S][64] packed, scaled
    const u16* __restrict__ Kk,     // [B*NKV][S][64]
    const u16* __restrict__ Vt,     // [B*NKV][64][S]
    u16* __restrict__ O)            // [B*S][NH*64]
{
    __shared__ u16 sK[3][64 * 64];
    __shared__ u16 sV[3][64 * 64];

    const int t = threadIdx.x;
    const int lane = t & 63, wid = t >> 6;
    const int hi = lane >> 5, lq = lane & 31;
    const int bid = blockIdx.x;
    // balanced pairing: bid & bid+256 qb's sum to 7
    const int qb = (bid < 256) ? (7 - (bid >> 6)) : ((bid >> 6) - 4);
    const int bh = bid & 63;
    const int b = bh >> 5, h = bh & 31;
    const int kvh = h >> 2;

    const u16* Kp = Kk + ((size_t)(b*NKV + kvh)) * (S_LEN * 64);
    const u16* Vp = Vt + ((size_t)(b*NKV + kvh)) * (64 * S_LEN);

    const int q0w = qb*256 + wid*32;        // wave's first q row
    const int qg  = q0w + lq;               // this lane's q row

    // Q B-operand frags: col=q=lq, k(d) = 16*kd + 8*hi + j
    const u16* Qrow = Q + (((size_t)bh) * S_LEN + qg) * 64 + 8*hi;
    bf16x8 qf[4];
    #pragma unroll
    for (int kd = 0; kd < 4; ++kd)
        qf[kd] = *(const bf16x8*)(Qrow + 16*kd);

    f32x16 accO0 = {}, accO1 = {};          // O[q=lq][d = crow(r,hi) + 32*dm]
    float m_run = 0.f, l_run = 0.f;

    const int ntB = 4*qb + 4;
    const int tmax_w = (q0w + 31) >> 6;     // last tile this wave needs

    auto stageKV = [&](int kt, int bi) {
        const int kv = kt << 6;
        const unsigned row = t >> 3, cb = (t & 7) << 4;
        const unsigned scb = cb ^ ((row & 7) << 4);   // pre-swizzled source
        llds16(Kp + (size_t)(kv + row) * 64 + (scb >> 1), &sK[bi][0] + t*8);
        llds16(Vp + (size_t)row * S_LEN + kv + (scb >> 1), &sV[bi][0] + t*8);
    };

    stageKV(0, 0);
    stageKV(1, 1);
    int cur = 0, st2 = 2;

    for (int tt = 0; tt < ntB; ++tt) {
        if (tt < ntB - 1) CBAR(2); else CBAR(0);
        if (tt + 2 < ntB) stageKV(tt + 2, st2);
        if (tt <= tmax_w) {
            const int kv0 = tt * 64;
            // ---- QK^T (swapped), acc pre-biased with -m_run: s' = QK - m_run
            const float nm = -m_run;
            f32x16 s0, s1;
            #pragma unroll
            for (int r = 0; r < 16; ++r) { s0[r] = nm; s1[r] = nm; }
            #pragma unroll
            for (int kd = 0; kd < 4; ++kd) {
                const unsigned bc = ((unsigned)(32*kd + 16*hi)) ^ ((lq & 7) << 4);
                bf16x8 k0 = *(const bf16x8*)((const char*)&sK[cur][0] + lq*128 + bc);
                bf16x8 k1 = *(const bf16x8*)((const char*)&sK[cur][0] + (32 + lq)*128 + bc);
                s0 = __builtin_amdgcn_mfma_f32_32x32x16_bf16(k0, qf[kd], s0, 0, 0, 0);
                s1 = __builtin_amdgcn_mfma_f32_32x32x16_bf16(k1, qf[kd], s1, 0, 0, 0);
            }
            // ---- causal mask (diagonal-overlapping tiles only)
            if (kv0 + 63 > q0w) {
                #pragma unroll
                for (int r = 0; r < 16; ++r) {
                    const int kvg = kv0 + (r & 3) + 8*(r >> 2) + 4*hi;
                    if (kvg > qg)      s0[r] = -INFINITY;
                    if (kvg + 32 > qg) s1[r] = -INFINITY;
                }
            }
            // ---- tile max (tree) + half-wave combine; tm relative to m_run
            float mx[8];
            #pragma unroll
            for (int r = 0; r < 8; ++r)
                mx[r] = fmaxf(fmaxf(s0[r], s0[r+8]), fmaxf(s1[r], s1[r+8]));
            float tm = fmaxf(fmaxf(fmaxf(mx[0], mx[1]), fmaxf(mx[2], mx[3])),
                             fmaxf(fmaxf(mx[4], mx[5]), fmaxf(mx[6], mx[7])));
            tm = fmaxf(tm, __shfl_xor(tm, 32));
            // ---- defer-max: rescale only when tile max outgrew m_run by >8
            if (!__all(tm <= 8.0f)) {
                const float dd = fmaxf(tm, 0.f);
                const float al = __builtin_amdgcn_exp2f(-dd);
                m_run += dd;
                l_run *= al;
                #pragma unroll
                for (int r = 0; r < 16; ++r) { accO0[r] *= al; accO1[r] *= al; }
                #pragma unroll
                for (int r = 0; r < 16; ++r) { s0[r] -= dd; s1[r] -= dd; }
            }
            // ---- P = exp2(s'), row-sum (tree)
            #pragma unroll
            for (int r = 0; r < 16; ++r) {
                s0[r] = __builtin_amdgcn_exp2f(s0[r]);
                s1[r] = __builtin_amdgcn_exp2f(s1[r]);
            }
            float sm[8];
            #pragma unroll
            for (int r = 0; r < 8; ++r)
                sm[r] = (s0[r] + s0[r+8]) + (s1[r] + s1[r+8]);
            float rs = ((sm[0]+sm[1]) + (sm[2]+sm[3])) + ((sm[4]+sm[5]) + (sm[6]+sm[7]));
            rs += __shfl_xor(rs, 32);
            l_run += rs;

            // ---- P->bf16 + half-wave exchange via permlane32_swap; PV MFMA
            #pragma unroll
            for (int ks = 0; ks < 4; ++ks) {
                const f32x16& e = (ks & 2) ? s1 : s0;
                const int rb = (ks & 1) * 8;
                unsigned x0 = cvtpk(e[rb + 0], e[rb + 1]);
                unsigned x1 = cvtpk(e[rb + 2], e[rb + 3]);
                unsigned y0 = cvtpk(e[rb + 4], e[rb + 5]);
                unsigned y1 = cvtpk(e[rb + 6], e[rb + 7]);
                plswap(x0, y0);   // -> pb.u[0], pb.u[2]
                plswap(x1, y1);   // -> pb.u[1], pb.u[3]
                union { unsigned u[4]; bf16x8 v; } pb;
                pb.u[0] = x0; pb.u[1] = x1; pb.u[2] = y0; pb.u[3] = y1;
                const unsigned bc = ((unsigned)(32*ks + 16*hi)) ^ ((lq & 7) << 4);
                bf16x8 v0 = *(const bf16x8*)((const char*)&sV[cur][0] + lq*128 + bc);
                bf16x8 v1 = *(const bf16x8*)((const char*)&sV[cur][0] + (32 + lq)*128 + bc);
                accO0 = __builtin_amdgcn_mfma_f32_32x32x16_bf16(v0, pb.v, accO0, 0, 0, 0);
                accO1 = __builtin_amdgcn_mfma_f32_32x32x16_bf16(v1, pb.v, accO1, 0, 0, 0);
            }
        }
        cur = (cur == 2) ? 0 : cur + 1;
        st2 = (st2 == 2) ? 0 : st2 + 1;
    }

    // ---- epilogue: normalize, write O[q][h*64 + d], d = 32dm + 8g + 4hi + (0..3)
    const float inv = 1.0f / l_run;
    u16* orow = O + (((size_t)(b * S_LEN) + q0w + lq)) * (NH*HD) + h*64;
    #pragma unroll
    for (int g = 0; g < 4; ++g) {
        uint2 w0, w1;
        w0.x = cvtpk(accO0[4*g + 0] * inv, accO0[4*g + 1] * inv);
        w0.y = cvtpk(accO0[4*g + 2] * inv, accO0[4*g + 3] * inv);
        *(uint2*)(orow + 8*g + 4*hi) = w0;
        w1.x = cvtpk(accO1[4*g + 0] * inv, accO1[4*g + 1] * inv);
        w1.y = cvtpk(accO1[4*g + 2] * inv, accO1[4*g + 3] * inv);
        *(uint2*)(orow + 32 + 8*g + 4*hi) = w1;
    }
}

// ---------------- host launcher ----------------
extern "C" void kernel_launch(void* const* d_in, const int* in_sizes, int n_in,
                              void* d_out, int out_size, void* d_ws, size_t ws_size,
                              hipStream_t stream) {
    const float* x  = (const float*)d_in[0];
    const float* Wq = (const float*)d_in[1];
    const float* bq = (const float*)d_in[2];
    const float* Wk = (const float*)d_in[3];
    const float* bk = (const float*)d_in[4];
    const float* Wv = (const float*)d_in[5];
    const float* bv = (const float*)d_in[6];
    const float* Wo = (const float*)d_in[7];
    const float* bo = (const float*)d_in[8];
    const float* kw = (const float*)d_in[9];

    uint8_t* ws = (uint8_t*)d_ws;
    u16*   xb    = (u16*)(ws);                    // 16 MiB
    u16*   wqkvb = (u16*)(ws + 16777216);         // 12 MiB
    u16*   wob   = (u16*)(ws + 29360128);         //  8 MiB
    u16*   qpk   = (u16*)(ws + 37748736);         // 16 MiB  [B*NH][S][64]
    u16*   kpk   = (u16*)(ws + 54525952);         //  4 MiB  [B*NKV][S][64]
    u16*   vlin  = (u16*)(ws + 58720256);         //  4 MiB  [4096][512]
    u16*   vtb   = (u16*)(ws + 62914560);         //  4 MiB  [B*NKV][64][S]
    u16*   ob    = (u16*)(ws + 67108864);         // 16 MiB  [B*S][2048]
    float* bqkv  = (float*)(ws + 83886080);       // 12 KiB
    float* rtab  = (float*)(ws + 83898368);       // 512 KiB

    // 1. convert inputs to bf16; bias concat; RoPE table
    cvt_all<<<9216, 256, 0, stream>>>(x, Wq, Wk, Wv, Wo, xb, wqkvb, wob);
    build_bqkv<<<12, 256, 0, stream>>>(bq, bk, bv, bqkv);
    rope_table<<<256, 256, 0, stream>>>(rtab);

    // 2. QKV projection + fused RoPE/scale/pack epilogue
    gemm_qkv<<<768, 256, 0, stream>>>(xb, wqkvb, bqkv, rtab, kw, qpk, kpk, vlin);

    // 3. transpose-pack V (bf16 -> bf16)
    pack_vt<<<dim3(32, 16), 256, 0, stream>>>(vlin, vtb);

    // 4. causal flash attention: 512 blocks (8 q-tiles x 64 bh), 8 waves each
    attn_fwd<<<dim3(512), dim3(512), 0, stream>>>(qpk, kpk, vtb, ob);

    // 5. output projection: d_out = ob @ Wo^T + bo
    gemm_bt<<<512, 256, 0, stream>>>(ob, wob, bo, (float*)d_out, NROWS, HID, HID);

    (void)in_sizes; (void)n_in; (void)out_size; (void)ws_size;
}

// Round 7
// 191.542 us; speedup vs baseline: 2.0708x; 1.0134x over previous
//
#include <hip/hip_runtime.h>
#include <stdint.h>

#define S_LEN 2048
#define HID   2048
#define NH    32
#define NKV   8
#define HD    64
#define BATCH 2
#define NROWS (BATCH * S_LEN)      // 4096
#define QKVN  (NH*HD + 2*NKV*HD)   // 3072

typedef unsigned short u16;
typedef __bf16 bf16_t;
typedef bf16_t bf16x8 __attribute__((ext_vector_type(8)));
typedef float  f32x4  __attribute__((ext_vector_type(4)));
typedef float  f32x16 __attribute__((ext_vector_type(16)));
typedef u16    u16x8  __attribute__((ext_vector_type(8)));

#define LOG2E 1.4426950408889634f

__device__ __forceinline__ u16 f2bf(float f) {
    union { float f; uint32_t u; } v; v.f = f;
    uint32_t u = v.u;
    return (u16)((u + 0x7fffu + ((u >> 16) & 1u)) >> 16);
}

__device__ __forceinline__ unsigned cvtpk(float a, float b) {
    unsigned r;
    asm("v_cvt_pk_bf16_f32 %0, %1, %2" : "=v"(r) : "v"(a), "v"(b));
    return r;
}

// v_permlane32_swap_b32 a, b:  a'[l>=32] = b[l-32];  b'[l<32] = a[l+32]  (HW-verified R5)
__device__ __forceinline__ void plswap(unsigned &a, unsigned &b) {
    asm volatile("v_permlane32_swap_b32 %0, %1" : "+v"(a), "+v"(b));
}

__device__ __forceinline__ void llds16(const void* g, void* l) {
    __builtin_amdgcn_global_load_lds(
        (const __attribute__((address_space(1))) void*)g,
        (__attribute__((address_space(3))) void*)l,
        16, 0, 0);
}

// counted-vmcnt barrier: wait for all but N newest VMEM ops, then raw barrier.
#define CBAR(N) do { \
    asm volatile("s_waitcnt vmcnt(" #N ")" ::: "memory"); \
    __builtin_amdgcn_s_barrier(); \
    __builtin_amdgcn_sched_barrier(0); \
} while (0)

// ---------------- fused prep: f32->bf16 convert (5 tensors) + RoPE table + bias concat ----------------
#define CVT_GROUPS 2359296            // 8-elem groups across x|Wq|Wk|Wv|Wo
__global__ void prep_all(const float* __restrict__ x, const float* __restrict__ wq,
                         const float* __restrict__ wk, const float* __restrict__ wv,
                         const float* __restrict__ wo,
                         const float* __restrict__ bq, const float* __restrict__ bk,
                         const float* __restrict__ bv,
                         u16* __restrict__ xb, u16* __restrict__ wqkvb, u16* __restrict__ wob,
                         float* __restrict__ rtab, float* __restrict__ bqkv) {
    int e = blockIdx.x * 256 + threadIdx.x;
    if (e < CVT_GROUPS) {
        const float* s; u16* d; int o;
        if (e < 1048576)      { s = x;  d = xb;                 o = e; }
        else if (e < 1572864) { s = wq; d = wqkvb;              o = e - 1048576; }
        else if (e < 1703936) { s = wk; d = wqkvb + 2048*2048;  o = e - 1572864; }
        else if (e < 1835008) { s = wv; d = wqkvb + 2560*2048;  o = e - 1703936; }
        else                  { s = wo; d = wob;                o = e - 1835008; }
        const float4* sp = (const float4*)s;
        float4 a = sp[2*(size_t)o], b = sp[2*(size_t)o + 1];
        u16x8 r;
        r[0]=f2bf(a.x); r[1]=f2bf(a.y); r[2]=f2bf(a.z); r[3]=f2bf(a.w);
        r[4]=f2bf(b.x); r[5]=f2bf(b.y); r[6]=f2bf(b.z); r[7]=f2bf(b.w);
        *(u16x8*)(d + 8*(size_t)o) = r;
    } else if (e < CVT_GROUPS + 65536) {
        int idx = e - CVT_GROUPS;          // s*32 + i
        int i = idx & 31, s = idx >> 5;
        float invf = exp2f(-(float)i * (13.287712379549449f / 32.0f));
        float ang = (float)s * invf;
        float sn, cs;
        sincosf(ang, &sn, &cs);
        rtab[idx] = cs;
        rtab[S_LEN*32 + idx] = sn;
    } else if (e < CVT_GROUPS + 65536 + QKVN) {
        int i = e - CVT_GROUPS - 65536;
        bqkv[i] = (i < 2048) ? bq[i] : (i < 2560 ? bk[i - 2048] : bv[i - 2560]);
    }
}

// =====================================================================================
// GEMM geometry (both GEMMs): block 128x256, 4 waves (2M x 2N), wave tile 64x128,
// BK=32, 3-buffer depth-2 counted pipeline, LDS XOR-swizzle ((row&3)<<4) on 64B rows.
// Per buf: A [128][32] bf16 (8KB) at u16 [0,4096), B [256][32] (16KB) at [4096,12288).
// =====================================================================================

// ---------------- QKV GEMM + fused RoPE/scale/pack epilogue ----------------
__global__ __launch_bounds__(256, 2) void gemm_qkv(
    const u16* __restrict__ A, const u16* __restrict__ Bw,
    const float* __restrict__ bias, const float* __restrict__ rtab,
    const float* __restrict__ kw,
    u16* __restrict__ qpk, u16* __restrict__ kpk, u16* __restrict__ vlin)
{
    const int M = NROWS, N = QKVN, K = HID;
    const int nbm = M >> 7, nbn = N >> 8;   // 32 x 12
    const int nwg = nbm * nbn;              // 384 (div by 8)
    int wg = blockIdx.x;
    wg = (wg & 7) * (nwg >> 3) + (wg >> 3); // XCD swizzle
    const int bm = wg % nbm, bn = wg / nbm;
    const int brow = bm << 7, bcol = bn << 8;

    __shared__ u16 sbuf[3][12288];          // 72 KB

    const int t = threadIdx.x;
    const int lane = t & 63, wid = t >> 6;
    const int wr = wid >> 1, wn = wid & 1;
    const int lr = lane & 15, lhi = lane >> 4;

    auto stage = [&](int kt, int bi) {
        const int k0 = kt << 5;
        #pragma unroll
        for (int i = 0; i < 2; ++i) {       // A: 8 KB
            const unsigned off = ((unsigned)t << 4) + ((unsigned)i << 12);
            const unsigned row = off >> 6;
            const unsigned scb = (off & 63) ^ ((row & 3) << 4);
            llds16(A + (size_t)(brow + row) * K + (k0 + (scb >> 1)), &sbuf[bi][0] + (off >> 1));
        }
        #pragma unroll
        for (int i = 0; i < 4; ++i) {       // B: 16 KB
            const unsigned off = ((unsigned)t << 4) + ((unsigned)i << 12);
            const unsigned row = off >> 6;
            const unsigned scb = (off & 63) ^ ((row & 3) << 4);
            llds16(Bw + (size_t)(bcol + row) * K + (k0 + (scb >> 1)), &sbuf[bi][4096] + (off >> 1));
        }
    };

    f32x4 acc[4][8] = {};
    const int nk = K >> 5;                  // 64

    stage(0, 0);
    stage(1, 1);
    int cur = 0, st2 = 2;
    for (int kt = 0; kt < nk; ++kt) {
        if (kt < nk - 1) CBAR(6); else CBAR(0);
        if (kt + 2 < nk) stage(kt + 2, st2);
        const char* sA = (const char*)&sbuf[cur][0];
        const char* sB = (const char*)&sbuf[cur][4096];
        bf16x8 af[4], bfv[8];
        #pragma unroll
        for (int m = 0; m < 4; ++m) {
            const int row = wr*64 + m*16 + lr;
            af[m] = *(const bf16x8*)(sA + row*64 + ((lhi*16) ^ ((row & 3) << 4)));
        }
        #pragma unroll
        for (int n = 0; n < 8; ++n) {
            const int row = wn*128 + n*16 + lr;
            bfv[n] = *(const bf16x8*)(sB + row*64 + ((lhi*16) ^ ((row & 3) << 4)));
        }
        #pragma unroll
        for (int m = 0; m < 4; ++m)
            #pragma unroll
            for (int n = 0; n < 8; ++n)
                acc[m][n] = __builtin_amdgcn_mfma_f32_16x16x32_bf16(af[m], bfv[n], acc[m][n], 0, 0, 0);
        cur = (cur == 2) ? 0 : cur + 1;
        st2 = (st2 == 2) ? 0 : st2 + 1;
    }

    const int rowb = brow + wr*64;
    #pragma unroll
    for (int hg = 0; hg < 2; ++hg) {        // two 64-col head blocks per wave
        const int c64 = bcol + wn*128 + hg*64;
        const int hb  = c64 >> 6;           // 0..47: <32 Q, <40 K, else V
        if (hb < 40) {
            const bool isQ = hb < 32;
            const float sc = isQ ? (0.125f * LOG2E * kw[hb]) : 1.0f;
            u16* dst = isQ ? qpk : kpk;
            const int nheads = isQ ? 32 : 8;
            const int hloc = isQ ? hb : (hb - 32);
            #pragma unroll
            for (int m = 0; m < 4; ++m) {
                #pragma unroll
                for (int nn = 0; nn < 2; ++nn) {
                    const int n = 4*hg + nn;
                    const int i = nn*16 + lr;
                    const float b1 = bias[c64 + i];
                    const float b2 = bias[c64 + i + 32];
                    #pragma unroll
                    for (int j = 0; j < 4; ++j) {
                        const int row = rowb + m*16 + lhi*4 + j;
                        const int s = row & (S_LEN - 1);
                        const int bb = row >> 11;
                        const float x1 = acc[m][n][j] + b1;
                        const float x2 = acc[m][n+2][j] + b2;
                        const float cs = rtab[s*32 + i];
                        const float sn = rtab[S_LEN*32 + s*32 + i];
                        const size_t base = ((size_t)(bb*nheads + hloc)) * (S_LEN*64) + (size_t)s*64;
                        dst[base + i]      = f2bf((x1*cs - x2*sn) * sc);
                        dst[base + i + 32] = f2bf((x2*cs + x1*sn) * sc);
                    }
                }
            }
        } else {
            #pragma unroll
            for (int m = 0; m < 4; ++m) {
                #pragma unroll
                for (int nn = 0; nn < 4; ++nn) {
                    const int col = c64 + nn*16 + lr;
                    const float bv = bias[col];
                    #pragma unroll
                    for (int j = 0; j < 4; ++j) {
                        const int row = rowb + m*16 + lhi*4 + j;
                        vlin[(size_t)row * 512 + (col - 2560)] = f2bf(acc[m][nn + 4*hg][j] + bv);
                    }
                }
            }
        }
    }
}

// ---------------- o-proj GEMM, C[M][N] = A @ Bw^T + bias (f32 out) ----------------
__global__ __launch_bounds__(256, 2) void gemm_bt(
    const u16* __restrict__ A, const u16* __restrict__ Bw,
    const float* __restrict__ bias, float* __restrict__ C,
    int M, int N, int K)
{
    const int nbm = M >> 7, nbn = N >> 8;
    const int nwg = nbm * nbn;
    int wg = blockIdx.x;
    wg = (wg & 7) * (nwg >> 3) + (wg >> 3);
    const int bm = wg % nbm, bn = wg / nbm;
    const int brow = bm << 7, bcol = bn << 8;

    __shared__ u16 sbuf[3][12288];

    const int t = threadIdx.x;
    const int lane = t & 63, wid = t >> 6;
    const int wr = wid >> 1, wn = wid & 1;
    const int lr = lane & 15, lhi = lane >> 4;

    auto stage = [&](int kt, int bi) {
        const int k0 = kt << 5;
        #pragma unroll
        for (int i = 0; i < 2; ++i) {
            const unsigned off = ((unsigned)t << 4) + ((unsigned)i << 12);
            const unsigned row = off >> 6;
            const unsigned scb = (off & 63) ^ ((row & 3) << 4);
            llds16(A + (size_t)(brow + row) * K + (k0 + (scb >> 1)), &sbuf[bi][0] + (off >> 1));
        }
        #pragma unroll
        for (int i = 0; i < 4; ++i) {
            const unsigned off = ((unsigned)t << 4) + ((unsigned)i << 12);
            const unsigned row = off >> 6;
            const unsigned scb = (off & 63) ^ ((row & 3) << 4);
            llds16(Bw + (size_t)(bcol + row) * K + (k0 + (scb >> 1)), &sbuf[bi][4096] + (off >> 1));
        }
    };

    f32x4 acc[4][8] = {};
    const int nk = K >> 5;

    stage(0, 0);
    stage(1, 1);
    int cur = 0, st2 = 2;
    for (int kt = 0; kt < nk; ++kt) {
        if (kt < nk - 1) CBAR(6); else CBAR(0);
        if (kt + 2 < nk) stage(kt + 2, st2);
        const char* sA = (const char*)&sbuf[cur][0];
        const char* sB = (const char*)&sbuf[cur][4096];
        bf16x8 af[4], bfv[8];
        #pragma unroll
        for (int m = 0; m < 4; ++m) {
            const int row = wr*64 + m*16 + lr;
            af[m] = *(const bf16x8*)(sA + row*64 + ((lhi*16) ^ ((row & 3) << 4)));
        }
        #pragma unroll
        for (int n = 0; n < 8; ++n) {
            const int row = wn*128 + n*16 + lr;
            bfv[n] = *(const bf16x8*)(sB + row*64 + ((lhi*16) ^ ((row & 3) << 4)));
        }
        #pragma unroll
        for (int m = 0; m < 4; ++m)
            #pragma unroll
            for (int n = 0; n < 8; ++n)
                acc[m][n] = __builtin_amdgcn_mfma_f32_16x16x32_bf16(af[m], bfv[n], acc[m][n], 0, 0, 0);
        cur = (cur == 2) ? 0 : cur + 1;
        st2 = (st2 == 2) ? 0 : st2 + 1;
    }

    #pragma unroll
    for (int m = 0; m < 4; ++m) {
        #pragma unroll
        for (int n = 0; n < 8; ++n) {
            const int col = bcol + wn*128 + n*16 + lr;
            const float bv = bias[col];
            #pragma unroll
            for (int j = 0; j < 4; ++j) {
                const int row = brow + wr*64 + m*16 + lhi*4 + j;
                C[(size_t)row * N + col] = acc[m][n][j] + bv;
            }
        }
    }
}

// ---------------- pack V transposed: bf16 vlin[row][512] -> vtb[b*8+kvh][64][S] ----------------
__global__ void pack_vt(const u16* __restrict__ vlin, u16* __restrict__ vtb) {
    __shared__ u16 tile[64][67];
    const int st = blockIdx.x;          // s-tile
    const int bk = blockIdx.y;          // b*8 + kvh
    const int t = threadIdx.x;
    const int b = bk >> 3, kvh = bk & 7;
    const int r = t >> 2, cg = (t & 3) << 4;
    const u16* src = vlin + ((size_t)(b*S_LEN + st*64 + r)) * 512 + kvh*64 + cg;
    #pragma unroll
    for (int j = 0; j < 16; ++j) tile[r][cg + j] = src[j];
    __syncthreads();
    const int d = t >> 2, sg = (t & 3) << 4;
    u16* dst = vtb + ((size_t)(bk*64 + d)) * S_LEN + st*64 + sg;
    #pragma unroll
    for (int j = 0; j < 16; ++j) dst[j] = tile[sg + j][d];
}

// ---------------- flash attention: 8 waves x 32 q-rows, swapped 32x32 MFMA ----------------
__global__ __launch_bounds__(512, 4) void attn_fwd(
    const u16* __restrict__ Q,      // [B*NH][S][64] packed, scaled
    const u16* __restrict__ Kk,     // [B*NKV][S][64]
    const u16* __restrict__ Vt,     // [B*NKV][64][S]
    u16* __restrict__ O)            // [B*S][NH*64]
{
    __shared__ u16 sK[3][64 * 64];
    __shared__ u16 sV[3][64 * 64];

    const int t = threadIdx.x;
    const int lane = t & 63, wid = t >> 6;
    const int hi = lane >> 5, lq = lane & 31;
    const int bid = blockIdx.x;
    const int qb = (bid < 256) ? (7 - (bid >> 6)) : ((bid >> 6) - 4);
    const int bh = bid & 63;
    const int b = bh >> 5, h = bh & 31;
    const int kvh = h >> 2;

    const u16* Kp = Kk + ((size_t)(b*NKV + kvh)) * (S_LEN * 64);
    const u16* Vp = Vt + ((size_t)(b*NKV + kvh)) * (64 * S_LEN);

    const int q0w = qb*256 + wid*32;
    const int qg  = q0w + lq;

    const u16* Qrow = Q + (((size_t)bh) * S_LEN + qg) * 64 + 8*hi;
    bf16x8 qf[4];
    #pragma unroll
    for (int kd = 0; kd < 4; ++kd)
        qf[kd] = *(const bf16x8*)(Qrow + 16*kd);

    f32x16 accO0 = {}, accO1 = {};
    float m_run = 0.f, l_run = 0.f;

    const int ntB = 4*qb + 4;
    const int tmax_w = (q0w + 31) >> 6;

    auto stageKV = [&](int kt, int bi) {
        const int kv = kt << 6;
        const unsigned row = t >> 3, cb = (t & 7) << 4;
        const unsigned scb = cb ^ ((row & 7) << 4);
        llds16(Kp + (size_t)(kv + row) * 64 + (scb >> 1), &sK[bi][0] + t*8);
        llds16(Vp + (size_t)row * S_LEN + kv + (scb >> 1), &sV[bi][0] + t*8);
    };

    stageKV(0, 0);
    stageKV(1, 1);
    int cur = 0, st2 = 2;

    for (int tt = 0; tt < ntB; ++tt) {
        if (tt < ntB - 1) CBAR(2); else CBAR(0);
        if (tt + 2 < ntB) stageKV(tt + 2, st2);
        if (tt <= tmax_w) {
            const int kv0 = tt * 64;
            const float nm = -m_run;
            f32x16 s0, s1;
            #pragma unroll
            for (int r = 0; r < 16; ++r) { s0[r] = nm; s1[r] = nm; }
            #pragma unroll
            for (int kd = 0; kd < 4; ++kd) {
                const unsigned bc = ((unsigned)(32*kd + 16*hi)) ^ ((lq & 7) << 4);
                bf16x8 k0 = *(const bf16x8*)((const char*)&sK[cur][0] + lq*128 + bc);
                bf16x8 k1 = *(const bf16x8*)((const char*)&sK[cur][0] + (32 + lq)*128 + bc);
                s0 = __builtin_amdgcn_mfma_f32_32x32x16_bf16(k0, qf[kd], s0, 0, 0, 0);
                s1 = __builtin_amdgcn_mfma_f32_32x32x16_bf16(k1, qf[kd], s1, 0, 0, 0);
            }
            if (kv0 + 63 > q0w) {
                #pragma unroll
                for (int r = 0; r < 16; ++r) {
                    const int kvg = kv0 + (r & 3) + 8*(r >> 2) + 4*hi;
                    if (kvg > qg)      s0[r] = -INFINITY;
                    if (kvg + 32 > qg) s1[r] = -INFINITY;
                }
            }
            float mx[8];
            #pragma unroll
            for (int r = 0; r < 8; ++r)
                mx[r] = fmaxf(fmaxf(s0[r], s0[r+8]), fmaxf(s1[r], s1[r+8]));
            float tm = fmaxf(fmaxf(fmaxf(mx[0], mx[1]), fmaxf(mx[2], mx[3])),
                             fmaxf(fmaxf(mx[4], mx[5]), fmaxf(mx[6], mx[7])));
            tm = fmaxf(tm, __shfl_xor(tm, 32));
            if (!__all(tm <= 8.0f)) {
                const float dd = fmaxf(tm, 0.f);
                const float al = __builtin_amdgcn_exp2f(-dd);
                m_run += dd;
                l_run *= al;
                #pragma unroll
                for (int r = 0; r < 16; ++r) { accO0[r] *= al; accO1[r] *= al; }
                #pragma unroll
                for (int r = 0; r < 16; ++r) { s0[r] -= dd; s1[r] -= dd; }
            }
            #pragma unroll
            for (int r = 0; r < 16; ++r) {
                s0[r] = __builtin_amdgcn_exp2f(s0[r]);
                s1[r] = __builtin_amdgcn_exp2f(s1[r]);
            }
            float sm[8];
            #pragma unroll
            for (int r = 0; r < 8; ++r)
                sm[r] = (s0[r] + s0[r+8]) + (s1[r] + s1[r+8]);
            float rs = ((sm[0]+sm[1]) + (sm[2]+sm[3])) + ((sm[4]+sm[5]) + (sm[6]+sm[7]));
            rs += __shfl_xor(rs, 32);
            l_run += rs;

            #pragma unroll
            for (int ks = 0; ks < 4; ++ks) {
                const f32x16& e = (ks & 2) ? s1 : s0;
                const int rb = (ks & 1) * 8;
                unsigned x0 = cvtpk(e[rb + 0], e[rb + 1]);
                unsigned x1 = cvtpk(e[rb + 2], e[rb + 3]);
                unsigned y0 = cvtpk(e[rb + 4], e[rb + 5]);
                unsigned y1 = cvtpk(e[rb + 6], e[rb + 7]);
                plswap(x0, y0);
                plswap(x1, y1);
                union { unsigned u[4]; bf16x8 v; } pb;
                pb.u[0] = x0; pb.u[1] = x1; pb.u[2] = y0; pb.u[3] = y1;
                const unsigned bc = ((unsigned)(32*ks + 16*hi)) ^ ((lq & 7) << 4);
                bf16x8 v0 = *(const bf16x8*)((const char*)&sV[cur][0] + lq*128 + bc);
                bf16x8 v1 = *(const bf16x8*)((const char*)&sV[cur][0] + (32 + lq)*128 + bc);
                accO0 = __builtin_amdgcn_mfma_f32_32x32x16_bf16(v0, pb.v, accO0, 0, 0, 0);
                accO1 = __builtin_amdgcn_mfma_f32_32x32x16_bf16(v1, pb.v, accO1, 0, 0, 0);
            }
        }
        cur = (cur == 2) ? 0 : cur + 1;
        st2 = (st2 == 2) ? 0 : st2 + 1;
    }

    const float inv = 1.0f / l_run;
    u16* orow = O + (((size_t)(b * S_LEN) + q0w + lq)) * (NH*HD) + h*64;
    #pragma unroll
    for (int g = 0; g < 4; ++g) {
        uint2 w0, w1;
        w0.x = cvtpk(accO0[4*g + 0] * inv, accO0[4*g + 1] * inv);
        w0.y = cvtpk(accO0[4*g + 2] * inv, accO0[4*g + 3] * inv);
        *(uint2*)(orow + 8*g + 4*hi) = w0;
        w1.x = cvtpk(accO1[4*g + 0] * inv, accO1[4*g + 1] * inv);
        w1.y = cvtpk(accO1[4*g + 2] * inv, accO1[4*g + 3] * inv);
        *(uint2*)(orow + 32 + 8*g + 4*hi) = w1;
    }
}

// ---------------- host launcher ----------------
extern "C" void kernel_launch(void* const* d_in, const int* in_sizes, int n_in,
                              void* d_out, int out_size, void* d_ws, size_t ws_size,
                              hipStream_t stream) {
    const float* x  = (const float*)d_in[0];
    const float* Wq = (const float*)d_in[1];
    const float* bq = (const float*)d_in[2];
    const float* Wk = (const float*)d_in[3];
    const float* bk = (const float*)d_in[4];
    const float* Wv = (const float*)d_in[5];
    const float* bv = (const float*)d_in[6];
    const float* Wo = (const float*)d_in[7];
    const float* bo = (const float*)d_in[8];
    const float* kw = (const float*)d_in[9];

    uint8_t* ws = (uint8_t*)d_ws;
    u16*   xb    = (u16*)(ws);                    // 16 MiB
    u16*   wqkvb = (u16*)(ws + 16777216);         // 12 MiB
    u16*   wob   = (u16*)(ws + 29360128);         //  8 MiB
    u16*   qpk   = (u16*)(ws + 37748736);         // 16 MiB  [B*NH][S][64]
    u16*   kpk   = (u16*)(ws + 54525952);         //  4 MiB  [B*NKV][S][64]
    u16*   vlin  = (u16*)(ws + 58720256);         //  4 MiB  [4096][512]
    u16*   vtb   = (u16*)(ws + 62914560);         //  4 MiB  [B*NKV][64][S]
    u16*   ob    = (u16*)(ws + 67108864);         // 16 MiB  [B*S][2048]
    float* bqkv  = (float*)(ws + 83886080);       // 12 KiB
    float* rtab  = (float*)(ws + 83898368);       // 512 KiB

    // 1. fused prep: bf16 converts + RoPE table + bias concat (one launch)
    prep_all<<<9484, 256, 0, stream>>>(x, Wq, Wk, Wv, Wo, bq, bk, bv,
                                       xb, wqkvb, wob, rtab, bqkv);

    // 2. QKV projection + fused RoPE/scale/pack epilogue (384 blocks, 128x256 tile)
    gemm_qkv<<<384, 256, 0, stream>>>(xb, wqkvb, bqkv, rtab, kw, qpk, kpk, vlin);

    // 3. transpose-pack V
    pack_vt<<<dim3(32, 16), 256, 0, stream>>>(vlin, vtb);

    // 4. causal flash attention
    attn_fwd<<<dim3(512), dim3(512), 0, stream>>>(qpk, kpk, vtb, ob);

    // 5. output projection (256 blocks, 128x256 tile)
    gemm_bt<<<256, 256, 0, stream>>>(ob, wob, bo, (float*)d_out, NROWS, HID, HID);

    (void)in_sizes; (void)n_in; (void)out_size; (void)ws_size;
}

// Round 8
// 184.976 us; speedup vs baseline: 2.1443x; 1.0355x over previous
//
#include <hip/hip_runtime.h>
#include <stdint.h>

#define S_LEN 2048
#define HID   2048
#define NH    32
#define NKV   8
#define HD    64
#define BATCH 2
#define NROWS (BATCH * S_LEN)      // 4096
#define QKVN  (NH*HD + 2*NKV*HD)   // 3072

typedef unsigned short u16;
typedef __bf16 bf16_t;
typedef bf16_t bf16x8 __attribute__((ext_vector_type(8)));
typedef float  f32x4  __attribute__((ext_vector_type(4)));
typedef float  f32x16 __attribute__((ext_vector_type(16)));
typedef u16    u16x8  __attribute__((ext_vector_type(8)));

#define LOG2E 1.4426950408889634f

__device__ __forceinline__ u16 f2bf(float f) {
    union { float f; uint32_t u; } v; v.f = f;
    uint32_t u = v.u;
    return (u16)((u + 0x7fffu + ((u >> 16) & 1u)) >> 16);
}

__device__ __forceinline__ unsigned cvtpk(float a, float b) {
    unsigned r;
    asm("v_cvt_pk_bf16_f32 %0, %1, %2" : "=v"(r) : "v"(a), "v"(b));
    return r;
}

// v_permlane32_swap_b32 a, b:  a'[l>=32] = b[l-32];  b'[l<32] = a[l+32]  (HW-verified R5)
__device__ __forceinline__ void plswap(unsigned &a, unsigned &b) {
    asm volatile("v_permlane32_swap_b32 %0, %1" : "+v"(a), "+v"(b));
}

__device__ __forceinline__ void llds16(const void* g, void* l) {
    __builtin_amdgcn_global_load_lds(
        (const __attribute__((address_space(1))) void*)g,
        (__attribute__((address_space(3))) void*)l,
        16, 0, 0);
}

#define LGKM0() do { asm volatile("s_waitcnt lgkmcnt(0)" ::: "memory"); \
                     __builtin_amdgcn_sched_barrier(0); } while (0)
#define BAR()   __builtin_amdgcn_s_barrier()

// counted-vmcnt barrier (attn): wait for all but N newest VMEM ops, then raw barrier.
#define CBAR(N) do { \
    asm volatile("s_waitcnt vmcnt(" #N ")" ::: "memory"); \
    __builtin_amdgcn_s_barrier(); \
    __builtin_amdgcn_sched_barrier(0); \
} while (0)

// ---------------- fused prep: f32->bf16 convert (5 tensors) + RoPE table + bias concat ----------------
#define CVT_GROUPS 2359296            // 8-elem groups across x|Wq|Wk|Wv|Wo
__global__ void prep_all(const float* __restrict__ x, const float* __restrict__ wq,
                         const float* __restrict__ wk, const float* __restrict__ wv,
                         const float* __restrict__ wo,
                         const float* __restrict__ bq, const float* __restrict__ bk,
                         const float* __restrict__ bv,
                         u16* __restrict__ xb, u16* __restrict__ wqkvb, u16* __restrict__ wob,
                         float* __restrict__ rtab, float* __restrict__ bqkv) {
    int e = blockIdx.x * 256 + threadIdx.x;
    if (e < CVT_GROUPS) {
        const float* s; u16* d; int o;
        if (e < 1048576)      { s = x;  d = xb;                 o = e; }
        else if (e < 1572864) { s = wq; d = wqkvb;              o = e - 1048576; }
        else if (e < 1703936) { s = wk; d = wqkvb + 2048*2048;  o = e - 1572864; }
        else if (e < 1835008) { s = wv; d = wqkvb + 2560*2048;  o = e - 1703936; }
        else                  { s = wo; d = wob;                o = e - 1835008; }
        const float4* sp = (const float4*)s;
        float4 a = sp[2*(size_t)o], b = sp[2*(size_t)o + 1];
        u16x8 r;
        r[0]=f2bf(a.x); r[1]=f2bf(a.y); r[2]=f2bf(a.z); r[3]=f2bf(a.w);
        r[4]=f2bf(b.x); r[5]=f2bf(b.y); r[6]=f2bf(b.z); r[7]=f2bf(b.w);
        *(u16x8*)(d + 8*(size_t)o) = r;
    } else if (e < CVT_GROUPS + 65536) {
        int idx = e - CVT_GROUPS;          // s*32 + i
        int i = idx & 31, s = idx >> 5;
        float invf = exp2f(-(float)i * (13.287712379549449f / 32.0f));
        float ang = (float)s * invf;
        float sn, cs;
        sincosf(ang, &sn, &cs);
        rtab[idx] = cs;
        rtab[S_LEN*32 + idx] = sn;
    } else if (e < CVT_GROUPS + 65536 + QKVN) {
        int i = e - CVT_GROUPS - 65536;
        bqkv[i] = (i < 2048) ? bq[i] : (i < 2560 ? bk[i - 2048] : bv[i - 2560]);
    }
}

// =====================================================================================
// GEMM geometry: block 128x256, 4 waves (2M x 2N), wave tile 64x128, BK=32,
// 3-buffer counted pipeline, phase-split K-step (2 phases: barrier/lgkm0/setprio/16 MFMA),
// LDS XOR-swizzle ((row&3)<<4), bm-major XCD chunking (A-panel fits per-XCD L2).
// =====================================================================================

// ---------------- QKV GEMM + fused RoPE/scale/pack epilogue ----------------
__global__ __launch_bounds__(256, 2) void gemm_qkv(
    const u16* __restrict__ A, const u16* __restrict__ Bw,
    const float* __restrict__ bias, const float* __restrict__ rtab,
    const float* __restrict__ kw,
    u16* __restrict__ qpk, u16* __restrict__ kpk, u16* __restrict__ vlin)
{
    const int M = NROWS, N = QKVN, K = HID;
    const int nbn = N >> 8;                 // 12
    const int nwg = (M >> 7) * nbn;         // 384
    int wg = blockIdx.x;
    wg = (wg & 7) * (nwg >> 3) + (wg >> 3); // XCD -> contiguous 48-chunk
    const int bm = wg / nbn, bn = wg % nbn; // bm-major: XCD sees 4 A-strips (2MB, L2-fit)
    const int brow = bm << 7, bcol = bn << 8;

    __shared__ u16 sbuf[3][12288];          // 72 KB

    const int t = threadIdx.x;
    const int lane = t & 63, wid = t >> 6;
    const int wr = wid >> 1, wn = wid & 1;
    const int lr = lane & 15, lhi = lane >> 4;

    auto stageA = [&](int kt, int bi) {     // A(2) + B0 (1)
        const int k0 = kt << 5;
        #pragma unroll
        for (int i = 0; i < 2; ++i) {
            const unsigned off = ((unsigned)t << 4) + ((unsigned)i << 12);
            const unsigned row = off >> 6;
            const unsigned scb = (off & 63) ^ ((row & 3) << 4);
            llds16(A + (size_t)(brow + row) * K + (k0 + (scb >> 1)), &sbuf[bi][0] + (off >> 1));
        }
        {
            const unsigned off = ((unsigned)t << 4);
            const unsigned row = off >> 6;
            const unsigned scb = (off & 63) ^ ((row & 3) << 4);
            llds16(Bw + (size_t)(bcol + row) * K + (k0 + (scb >> 1)), &sbuf[bi][4096] + (off >> 1));
        }
    };
    auto stageB = [&](int kt, int bi) {     // B1..B3 (3)
        const int k0 = kt << 5;
        #pragma unroll
        for (int i = 1; i < 4; ++i) {
            const unsigned off = ((unsigned)t << 4) + ((unsigned)i << 12);
            const unsigned row = off >> 6;
            const unsigned scb = (off & 63) ^ ((row & 3) << 4);
            llds16(Bw + (size_t)(bcol + row) * K + (k0 + (scb >> 1)), &sbuf[bi][4096] + (off >> 1));
        }
    };

    f32x4 acc[4][8] = {};
    const int nk = K >> 5;                  // 64

    stageA(0, 0); stageB(0, 0);
    stageA(1, 1); stageB(1, 1);
    asm volatile("s_waitcnt vmcnt(6)" ::: "memory");  // tile 0 resident
    BAR();

    int cur = 0, st2 = 2;
    for (int kt = 0; kt < nk; ++kt) {
        const char* sA = (const char*)&sbuf[cur][0];
        const char* sB = (const char*)&sbuf[cur][4096];
        bf16x8 af[4], bfv[8];
        // ---- phase A: reads + stage-issue, barrier, MFMA n=0..3 ----
        #pragma unroll
        for (int m = 0; m < 4; ++m) {
            const int row = wr*64 + m*16 + lr;
            af[m] = *(const bf16x8*)(sA + row*64 + ((lhi*16) ^ ((row & 3) << 4)));
        }
        #pragma unroll
        for (int n = 0; n < 4; ++n) {
            const int row = wn*128 + n*16 + lr;
            bfv[n] = *(const bf16x8*)(sB + row*64 + ((lhi*16) ^ ((row & 3) << 4)));
        }
        if (kt + 2 < nk) stageA(kt + 2, st2);
        BAR();
        LGKM0();
        __builtin_amdgcn_s_setprio(1);
        #pragma unroll
        for (int m = 0; m < 4; ++m)
            #pragma unroll
            for (int n = 0; n < 4; ++n)
                acc[m][n] = __builtin_amdgcn_mfma_f32_16x16x32_bf16(af[m], bfv[n], acc[m][n], 0, 0, 0);
        __builtin_amdgcn_s_setprio(0);
        BAR();
        // ---- phase B: reads + stage-issue, barrier, MFMA n=4..7 ----
        #pragma unroll
        for (int n = 4; n < 8; ++n) {
            const int row = wn*128 + n*16 + lr;
            bfv[n] = *(const bf16x8*)(sB + row*64 + ((lhi*16) ^ ((row & 3) << 4)));
        }
        if (kt + 2 < nk) stageB(kt + 2, st2);
        BAR();
        LGKM0();
        __builtin_amdgcn_s_setprio(1);
        #pragma unroll
        for (int m = 0; m < 4; ++m)
            #pragma unroll
            for (int n = 4; n < 8; ++n)
                acc[m][n] = __builtin_amdgcn_mfma_f32_16x16x32_bf16(af[m], bfv[n], acc[m][n], 0, 0, 0);
        __builtin_amdgcn_s_setprio(0);
        // ---- closing: ensure next tile resident, then barrier ----
        if (kt + 2 < nk) {
            asm volatile("s_waitcnt vmcnt(6)" ::: "memory");
            BAR();
        } else if (kt + 1 < nk) {
            asm volatile("s_waitcnt vmcnt(0)" ::: "memory");
            BAR();
        }
        cur = (cur == 2) ? 0 : cur + 1;
        st2 = (st2 == 2) ? 0 : st2 + 1;
    }

    const int rowb = brow + wr*64;
    #pragma unroll
    for (int hg = 0; hg < 2; ++hg) {        // two 64-col head blocks per wave
        const int c64 = bcol + wn*128 + hg*64;
        const int hb  = c64 >> 6;           // 0..47: <32 Q, <40 K, else V
        if (hb < 40) {
            const bool isQ = hb < 32;
            const float sc = isQ ? (0.125f * LOG2E * kw[hb]) : 1.0f;
            u16* dst = isQ ? qpk : kpk;
            const int nheads = isQ ? 32 : 8;
            const int hloc = isQ ? hb : (hb - 32);
            #pragma unroll
            for (int m = 0; m < 4; ++m) {
                #pragma unroll
                for (int nn = 0; nn < 2; ++nn) {
                    const int n = 4*hg + nn;
                    const int i = nn*16 + lr;
                    const float b1 = bias[c64 + i];
                    const float b2 = bias[c64 + i + 32];
                    #pragma unroll
                    for (int j = 0; j < 4; ++j) {
                        const int row = rowb + m*16 + lhi*4 + j;
                        const int s = row & (S_LEN - 1);
                        const int bb = row >> 11;
                        const float x1 = acc[m][n][j] + b1;
                        const float x2 = acc[m][n+2][j] + b2;
                        const float cs = rtab[s*32 + i];
                        const float sn = rtab[S_LEN*32 + s*32 + i];
                        const size_t base = ((size_t)(bb*nheads + hloc)) * (S_LEN*64) + (size_t)s*64;
                        dst[base + i]      = f2bf((x1*cs - x2*sn) * sc);
                        dst[base + i + 32] = f2bf((x2*cs + x1*sn) * sc);
                    }
                }
            }
        } else {
            #pragma unroll
            for (int m = 0; m < 4; ++m) {
                #pragma unroll
                for (int nn = 0; nn < 4; ++nn) {
                    const int col = c64 + nn*16 + lr;
                    const float bv = bias[col];
                    #pragma unroll
                    for (int j = 0; j < 4; ++j) {
                        const int row = rowb + m*16 + lhi*4 + j;
                        vlin[(size_t)row * 512 + (col - 2560)] = f2bf(acc[m][nn + 4*hg][j] + bv);
                    }
                }
            }
        }
    }
}

// ---------------- o-proj GEMM, C[M][N] = A @ Bw^T + bias (f32 out) ----------------
__global__ __launch_bounds__(256, 2) void gemm_bt(
    const u16* __restrict__ A, const u16* __restrict__ Bw,
    const float* __restrict__ bias, float* __restrict__ C,
    int M, int N, int K)
{
    const int nbn = N >> 8;
    const int nwg = (M >> 7) * nbn;
    int wg = blockIdx.x;
    wg = (wg & 7) * (nwg >> 3) + (wg >> 3);
    const int bm = wg / nbn, bn = wg % nbn;
    const int brow = bm << 7, bcol = bn << 8;

    __shared__ u16 sbuf[3][12288];

    const int t = threadIdx.x;
    const int lane = t & 63, wid = t >> 6;
    const int wr = wid >> 1, wn = wid & 1;
    const int lr = lane & 15, lhi = lane >> 4;

    auto stageA = [&](int kt, int bi) {
        const int k0 = kt << 5;
        #pragma unroll
        for (int i = 0; i < 2; ++i) {
            const unsigned off = ((unsigned)t << 4) + ((unsigned)i << 12);
            const unsigned row = off >> 6;
            const unsigned scb = (off & 63) ^ ((row & 3) << 4);
            llds16(A + (size_t)(brow + row) * K + (k0 + (scb >> 1)), &sbuf[bi][0] + (off >> 1));
        }
        {
            const unsigned off = ((unsigned)t << 4);
            const unsigned row = off >> 6;
            const unsigned scb = (off & 63) ^ ((row & 3) << 4);
            llds16(Bw + (size_t)(bcol + row) * K + (k0 + (scb >> 1)), &sbuf[bi][4096] + (off >> 1));
        }
    };
    auto stageB = [&](int kt, int bi) {
        const int k0 = kt << 5;
        #pragma unroll
        for (int i = 1; i < 4; ++i) {
            const unsigned off = ((unsigned)t << 4) + ((unsigned)i << 12);
            const unsigned row = off >> 6;
            const unsigned scb = (off & 63) ^ ((row & 3) << 4);
            llds16(Bw + (size_t)(bcol + row) * K + (k0 + (scb >> 1)), &sbuf[bi][4096] + (off >> 1));
        }
    };

    f32x4 acc[4][8] = {};
    const int nk = K >> 5;

    stageA(0, 0); stageB(0, 0);
    stageA(1, 1); stageB(1, 1);
    asm volatile("s_waitcnt vmcnt(6)" ::: "memory");
    BAR();

    int cur = 0, st2 = 2;
    for (int kt = 0; kt < nk; ++kt) {
        const char* sA = (const char*)&sbuf[cur][0];
        const char* sB = (const char*)&sbuf[cur][4096];
        bf16x8 af[4], bfv[8];
        #pragma unroll
        for (int m = 0; m < 4; ++m) {
            const int row = wr*64 + m*16 + lr;
            af[m] = *(const bf16x8*)(sA + row*64 + ((lhi*16) ^ ((row & 3) << 4)));
        }
        #pragma unroll
        for (int n = 0; n < 4; ++n) {
            const int row = wn*128 + n*16 + lr;
            bfv[n] = *(const bf16x8*)(sB + row*64 + ((lhi*16) ^ ((row & 3) << 4)));
        }
        if (kt + 2 < nk) stageA(kt + 2, st2);
        BAR();
        LGKM0();
        __builtin_amdgcn_s_setprio(1);
        #pragma unroll
        for (int m = 0; m < 4; ++m)
            #pragma unroll
            for (int n = 0; n < 4; ++n)
                acc[m][n] = __builtin_amdgcn_mfma_f32_16x16x32_bf16(af[m], bfv[n], acc[m][n], 0, 0, 0);
        __builtin_amdgcn_s_setprio(0);
        BAR();
        #pragma unroll
        for (int n = 4; n < 8; ++n) {
            const int row = wn*128 + n*16 + lr;
            bfv[n] = *(const bf16x8*)(sB + row*64 + ((lhi*16) ^ ((row & 3) << 4)));
        }
        if (kt + 2 < nk) stageB(kt + 2, st2);
        BAR();
        LGKM0();
        __builtin_amdgcn_s_setprio(1);
        #pragma unroll
        for (int m = 0; m < 4; ++m)
            #pragma unroll
            for (int n = 4; n < 8; ++n)
                acc[m][n] = __builtin_amdgcn_mfma_f32_16x16x32_bf16(af[m], bfv[n], acc[m][n], 0, 0, 0);
        __builtin_amdgcn_s_setprio(0);
        if (kt + 2 < nk) {
            asm volatile("s_waitcnt vmcnt(6)" ::: "memory");
            BAR();
        } else if (kt + 1 < nk) {
            asm volatile("s_waitcnt vmcnt(0)" ::: "memory");
            BAR();
        }
        cur = (cur == 2) ? 0 : cur + 1;
        st2 = (st2 == 2) ? 0 : st2 + 1;
    }

    #pragma unroll
    for (int m = 0; m < 4; ++m) {
        #pragma unroll
        for (int n = 0; n < 8; ++n) {
            const int col = bcol + wn*128 + n*16 + lr;
            const float bv = bias[col];
            #pragma unroll
            for (int j = 0; j < 4; ++j) {
                const int row = brow + wr*64 + m*16 + lhi*4 + j;
                C[(size_t)row * N + col] = acc[m][n][j] + bv;
            }
        }
    }
}

// ---------------- pack V transposed: bf16 vlin[row][512] -> vtb[b*8+kvh][64][S] ----------------
__global__ void pack_vt(const u16* __restrict__ vlin, u16* __restrict__ vtb) {
    __shared__ u16 tile[64][67];
    const int st = blockIdx.x;          // s-tile
    const int bk = blockIdx.y;          // b*8 + kvh
    const int t = threadIdx.x;
    const int b = bk >> 3, kvh = bk & 7;
    const int r = t >> 2, cg = (t & 3) << 4;
    const u16* src = vlin + ((size_t)(b*S_LEN + st*64 + r)) * 512 + kvh*64 + cg;
    #pragma unroll
    for (int j = 0; j < 16; ++j) tile[r][cg + j] = src[j];
    __syncthreads();
    const int d = t >> 2, sg = (t & 3) << 4;
    u16* dst = vtb + ((size_t)(bk*64 + d)) * S_LEN + st*64 + sg;
    #pragma unroll
    for (int j = 0; j < 16; ++j) dst[j] = tile[sg + j][d];
}

// ---------------- flash attention: 8 waves x 32 q-rows, swapped 32x32 MFMA ----------------
__global__ __launch_bounds__(512, 4) void attn_fwd(
    const u16* __restrict__ Q,      // [B*NH][S][64] packed, scaled
    const u16* __restrict__ Kk,     // [B*NKV][S][64]
    const u16* __restrict__ Vt,     // [B*NKV][64][S]
    u16* __restrict__ O)            // [B*S][NH*64]
{
    __shared__ u16 sK[3][64 * 64];
    __shared__ u16 sV[3][64 * 64];

    const int t = threadIdx.x;
    const int lane = t & 63, wid = t >> 6;
    const int hi = lane >> 5, lq = lane & 31;
    const int bid = blockIdx.x;
    const int qb = (bid < 256) ? (7 - (bid >> 6)) : ((bid >> 6) - 4);
    const int bh = bid & 63;
    const int b = bh >> 5, h = bh & 31;
    const int kvh = h >> 2;

    const u16* Kp = Kk + ((size_t)(b*NKV + kvh)) * (S_LEN * 64);
    const u16* Vp = Vt + ((size_t)(b*NKV + kvh)) * (64 * S_LEN);

    const int q0w = qb*256 + wid*32;
    const int qg  = q0w + lq;

    const u16* Qrow = Q + (((size_t)bh) * S_LEN + qg) * 64 + 8*hi;
    bf16x8 qf[4];
    #pragma unroll
    for (int kd = 0; kd < 4; ++kd)
        qf[kd] = *(const bf16x8*)(Qrow + 16*kd);

    f32x16 accO0 = {}, accO1 = {};
    float m_run = 0.f, l_run = 0.f;

    const int ntB = 4*qb + 4;
    const int tmax_w = (q0w + 31) >> 6;

    auto stageKV = [&](int kt, int bi) {
        const int kv = kt << 6;
        const unsigned row = t >> 3, cb = (t & 7) << 4;
        const unsigned scb = cb ^ ((row & 7) << 4);
        llds16(Kp + (size_t)(kv + row) * 64 + (scb >> 1), &sK[bi][0] + t*8);
        llds16(Vp + (size_t)row * S_LEN + kv + (scb >> 1), &sV[bi][0] + t*8);
    };

    stageKV(0, 0);
    stageKV(1, 1);
    int cur = 0, st2 = 2;

    for (int tt = 0; tt < ntB; ++tt) {
        if (tt < ntB - 1) CBAR(2); else CBAR(0);
        if (tt + 2 < ntB) stageKV(tt + 2, st2);
        if (tt <= tmax_w) {
            const int kv0 = tt * 64;
            const float nm = -m_run;
            f32x16 s0, s1;
            #pragma unroll
            for (int r = 0; r < 16; ++r) { s0[r] = nm; s1[r] = nm; }
            __builtin_amdgcn_s_setprio(1);
            #pragma unroll
            for (int kd = 0; kd < 4; ++kd) {
                const unsigned bc = ((unsigned)(32*kd + 16*hi)) ^ ((lq & 7) << 4);
                bf16x8 k0 = *(const bf16x8*)((const char*)&sK[cur][0] + lq*128 + bc);
                bf16x8 k1 = *(const bf16x8*)((const char*)&sK[cur][0] + (32 + lq)*128 + bc);
                s0 = __builtin_amdgcn_mfma_f32_32x32x16_bf16(k0, qf[kd], s0, 0, 0, 0);
                s1 = __builtin_amdgcn_mfma_f32_32x32x16_bf16(k1, qf[kd], s1, 0, 0, 0);
            }
            __builtin_amdgcn_s_setprio(0);
            if (kv0 + 63 > q0w) {
                #pragma unroll
                for (int r = 0; r < 16; ++r) {
                    const int kvg = kv0 + (r & 3) + 8*(r >> 2) + 4*hi;
                    if (kvg > qg)      s0[r] = -INFINITY;
                    if (kvg + 32 > qg) s1[r] = -INFINITY;
                }
            }
            float mx[8];
            #pragma unroll
            for (int r = 0; r < 8; ++r)
                mx[r] = fmaxf(fmaxf(s0[r], s0[r+8]), fmaxf(s1[r], s1[r+8]));
            float tm = fmaxf(fmaxf(fmaxf(mx[0], mx[1]), fmaxf(mx[2], mx[3])),
                             fmaxf(fmaxf(mx[4], mx[5]), fmaxf(mx[6], mx[7])));
            tm = fmaxf(tm, __shfl_xor(tm, 32));
            if (!__all(tm <= 8.0f)) {
                const float dd = fmaxf(tm, 0.f);
                const float al = __builtin_amdgcn_exp2f(-dd);
                m_run += dd;
                l_run *= al;
                #pragma unroll
                for (int r = 0; r < 16; ++r) { accO0[r] *= al; accO1[r] *= al; }
                #pragma unroll
                for (int r = 0; r < 16; ++r) { s0[r] -= dd; s1[r] -= dd; }
            }
            #pragma unroll
            for (int r = 0; r < 16; ++r) {
                s0[r] = __builtin_amdgcn_exp2f(s0[r]);
                s1[r] = __builtin_amdgcn_exp2f(s1[r]);
            }
            float sm[8];
            #pragma unroll
            for (int r = 0; r < 8; ++r)
                sm[r] = (s0[r] + s0[r+8]) + (s1[r] + s1[r+8]);
            float rs = ((sm[0]+sm[1]) + (sm[2]+sm[3])) + ((sm[4]+sm[5]) + (sm[6]+sm[7]));
            rs += __shfl_xor(rs, 32);
            l_run += rs;

            #pragma unroll
            for (int ks = 0; ks < 4; ++ks) {
                const f32x16& e = (ks & 2) ? s1 : s0;
                const int rb = (ks & 1) * 8;
                unsigned x0 = cvtpk(e[rb + 0], e[rb + 1]);
                unsigned x1 = cvtpk(e[rb + 2], e[rb + 3]);
                unsigned y0 = cvtpk(e[rb + 4], e[rb + 5]);
                unsigned y1 = cvtpk(e[rb + 6], e[rb + 7]);
                plswap(x0, y0);
                plswap(x1, y1);
                union { unsigned u[4]; bf16x8 v; } pb;
                pb.u[0] = x0; pb.u[1] = x1; pb.u[2] = y0; pb.u[3] = y1;
                const unsigned bc = ((unsigned)(32*ks + 16*hi)) ^ ((lq & 7) << 4);
                bf16x8 v0 = *(const bf16x8*)((const char*)&sV[cur][0] + lq*128 + bc);
                bf16x8 v1 = *(const bf16x8*)((const char*)&sV[cur][0] + (32 + lq)*128 + bc);
                __builtin_amdgcn_s_setprio(1);
                accO0 = __builtin_amdgcn_mfma_f32_32x32x16_bf16(v0, pb.v, accO0, 0, 0, 0);
                accO1 = __builtin_amdgcn_mfma_f32_32x32x16_bf16(v1, pb.v, accO1, 0, 0, 0);
                __builtin_amdgcn_s_setprio(0);
            }
        }
        cur = (cur == 2) ? 0 : cur + 1;
        st2 = (st2 == 2) ? 0 : st2 + 1;
    }

    const float inv = 1.0f / l_run;
    u16* orow = O + (((size_t)(b * S_LEN) + q0w + lq)) * (NH*HD) + h*64;
    #pragma unroll
    for (int g = 0; g < 4; ++g) {
        uint2 w0, w1;
        w0.x = cvtpk(accO0[4*g + 0] * inv, accO0[4*g + 1] * inv);
        w0.y = cvtpk(accO0[4*g + 2] * inv, accO0[4*g + 3] * inv);
        *(uint2*)(orow + 8*g + 4*hi) = w0;
        w1.x = cvtpk(accO1[4*g + 0] * inv, accO1[4*g + 1] * inv);
        w1.y = cvtpk(accO1[4*g + 2] * inv, accO1[4*g + 3] * inv);
        *(uint2*)(orow + 32 + 8*g + 4*hi) = w1;
    }
}

// ---------------- host launcher ----------------
extern "C" void kernel_launch(void* const* d_in, const int* in_sizes, int n_in,
                              void* d_out, int out_size, void* d_ws, size_t ws_size,
                              hipStream_t stream) {
    const float* x  = (const float*)d_in[0];
    const float* Wq = (const float*)d_in[1];
    const float* bq = (const float*)d_in[2];
    const float* Wk = (const float*)d_in[3];
    const float* bk = (const float*)d_in[4];
    const float* Wv = (const float*)d_in[5];
    const float* bv = (const float*)d_in[6];
    const float* Wo = (const float*)d_in[7];
    const float* bo = (const float*)d_in[8];
    const float* kw = (const float*)d_in[9];

    uint8_t* ws = (uint8_t*)d_ws;
    u16*   xb    = (u16*)(ws);                    // 16 MiB
    u16*   wqkvb = (u16*)(ws + 16777216);         // 12 MiB
    u16*   wob   = (u16*)(ws + 29360128);         //  8 MiB
    u16*   qpk   = (u16*)(ws + 37748736);         // 16 MiB  [B*NH][S][64]
    u16*   kpk   = (u16*)(ws + 54525952);         //  4 MiB  [B*NKV][S][64]
    u16*   vlin  = (u16*)(ws + 58720256);         //  4 MiB  [4096][512]
    u16*   vtb   = (u16*)(ws + 62914560);         //  4 MiB  [B*NKV][64][S]
    u16*   ob    = (u16*)(ws + 67108864);         // 16 MiB  [B*S][2048]
    float* bqkv  = (float*)(ws + 83886080);       // 12 KiB
    float* rtab  = (float*)(ws + 83898368);       // 512 KiB

    // 1. fused prep
    prep_all<<<9484, 256, 0, stream>>>(x, Wq, Wk, Wv, Wo, bq, bk, bv,
                                       xb, wqkvb, wob, rtab, bqkv);

    // 2. QKV projection + fused RoPE/scale/pack epilogue
    gemm_qkv<<<384, 256, 0, stream>>>(xb, wqkvb, bqkv, rtab, kw, qpk, kpk, vlin);

    // 3. transpose-pack V
    pack_vt<<<dim3(32, 16), 256, 0, stream>>>(vlin, vtb);

    // 4. causal flash attention
    attn_fwd<<<dim3(512), dim3(512), 0, stream>>>(qpk, kpk, vtb, ob);

    // 5. output projection
    gemm_bt<<<256, 256, 0, stream>>>(ob, wob, bo, (float*)d_out, NROWS, HID, HID);

    (void)in_sizes; (void)n_in; (void)out_size; (void)ws_size;
}